// Round 11
// baseline (157.141 us; speedup 1.0000x reference)
//
#include <hip/hip_runtime.h>
#include <math.h>

#define CB 8
#define CNX 512
#define CNR 512
#define CD 256
#define CH 256

typedef __attribute__((ext_vector_type(8))) short short8;
typedef __attribute__((ext_vector_type(4))) float f32x4;
typedef __attribute__((ext_vector_type(4))) unsigned int uint32x4;

__device__ __forceinline__ float fast_rcp(float x) {
#if __has_builtin(__builtin_amdgcn_rcpf)
  return __builtin_amdgcn_rcpf(x);
#else
  return 1.0f / x;
#endif
}
__device__ __forceinline__ float fast_exp2(float x) {
#if __has_builtin(__builtin_amdgcn_exp2f)
  return __builtin_amdgcn_exp2f(x);
#else
  return exp2f(x);
#endif
}

// Split 8 consecutive fp32 (two float4) into bf16 hi / lo short8 frags,
// fully in registers (bit_cast, no address-taken locals -> no scratch).
__device__ __forceinline__ void split8(float4 u, float4 v, short8* H, short8* L) {
  unsigned ux = __float_as_uint(u.x), uy = __float_as_uint(u.y);
  unsigned uz = __float_as_uint(u.z), uw = __float_as_uint(u.w);
  unsigned vx = __float_as_uint(v.x), vy = __float_as_uint(v.y);
  unsigned vz = __float_as_uint(v.z), vw = __float_as_uint(v.w);
  uint32x4 Hp = {(ux >> 16) | (uy & 0xFFFF0000u),
                 (uz >> 16) | (uw & 0xFFFF0000u),
                 (vx >> 16) | (vy & 0xFFFF0000u),
                 (vz >> 16) | (vw & 0xFFFF0000u)};
  float rux = u.x - __uint_as_float(ux & 0xFFFF0000u);
  float ruy = u.y - __uint_as_float(uy & 0xFFFF0000u);
  float ruz = u.z - __uint_as_float(uz & 0xFFFF0000u);
  float ruw = u.w - __uint_as_float(uw & 0xFFFF0000u);
  float rvx = v.x - __uint_as_float(vx & 0xFFFF0000u);
  float rvy = v.y - __uint_as_float(vy & 0xFFFF0000u);
  float rvz = v.z - __uint_as_float(vz & 0xFFFF0000u);
  float rvw = v.w - __uint_as_float(vw & 0xFFFF0000u);
  uint32x4 Lp = {(__float_as_uint(rux) >> 16) | (__float_as_uint(ruy) & 0xFFFF0000u),
                 (__float_as_uint(ruz) >> 16) | (__float_as_uint(ruw) & 0xFFFF0000u),
                 (__float_as_uint(rvx) >> 16) | (__float_as_uint(rvy) & 0xFFFF0000u),
                 (__float_as_uint(rvz) >> 16) | (__float_as_uint(rvw) & 0xFFFF0000u)};
  *H = __builtin_bit_cast(short8, Hp);
  *L = __builtin_bit_cast(short8, Lp);
}

// Split float4 -> bf16 hi ushort4 + lo ushort4 (truncation + residual).
__device__ __forceinline__ void split4(float4 v, ushort4* H, ushort4* L) {
  unsigned ux = __float_as_uint(v.x), uy = __float_as_uint(v.y);
  unsigned uz = __float_as_uint(v.z), uw = __float_as_uint(v.w);
  H->x = (unsigned short)(ux >> 16);
  H->y = (unsigned short)(uy >> 16);
  H->z = (unsigned short)(uz >> 16);
  H->w = (unsigned short)(uw >> 16);
  float rx = v.x - __uint_as_float(ux & 0xFFFF0000u);
  float ry = v.y - __uint_as_float(uy & 0xFFFF0000u);
  float rz = v.z - __uint_as_float(uz & 0xFFFF0000u);
  float rw = v.w - __uint_as_float(uw & 0xFFFF0000u);
  L->x = (unsigned short)(__float_as_uint(rx) >> 16);
  L->y = (unsigned short)(__float_as_uint(ry) >> 16);
  L->z = (unsigned short)(__float_as_uint(rz) >> 16);
  L->w = (unsigned short)(__float_as_uint(rw) >> 16);
}

// Fused projections via split-bf16 MFMA, LDS-FREE: A (X rows) and B (W rows)
// fragments load DIRECTLY from global (row = lane&15, k = q*8+j -> 16B/lane,
// 64B/row fully-used lines, L2-resident). In-register split8, no barriers.
// 64(m) x 64(h) tile, K-step 32, grid (64,4,2), block 256 = 4 waves,
// each wave a 32x32 quadrant (2x2 MFMA 16x16x32 frags).
__global__ __launch_bounds__(256) void proj_mfma(
    const float* __restrict__ A0, const float* __restrict__ A1,
    const float* __restrict__ W0, const float* __restrict__ W1,
    const float* __restrict__ bias0, const float* __restrict__ bias1,
    float* __restrict__ E0, float* __restrict__ E1) {
  int z = blockIdx.z;
  const float* A = z ? A1 : A0;
  const float* W = z ? W1 : W0;
  const float* bias = z ? bias1 : bias0;
  float* ET = z ? E1 : E0;
  int m0 = blockIdx.x * 64, n0 = blockIdx.y * 64;
  int tid = threadIdx.x;
  int lane = tid & 63, w = tid >> 6;
  int wm = w >> 1, wn = w & 1;  // wave quadrant: m-half, n-half
  int q = lane >> 4, ml = lane & 15;
  const float* pA = A + (size_t)(m0 + wm * 32 + ml) * CD + q * 8;
  const float* pW = W + (size_t)(n0 + wn * 32 + ml) * CD + q * 8;
  f32x4 acc[2][2] = {};
  for (int s = 0; s < 8; s++) {
    int kt = s * 32;
    float4 a0a = *(const float4*)(pA + kt);
    float4 a0b = *(const float4*)(pA + kt + 4);
    float4 a1a = *(const float4*)(pA + 16 * CD + kt);
    float4 a1b = *(const float4*)(pA + 16 * CD + kt + 4);
    float4 w0a = *(const float4*)(pW + kt);
    float4 w0b = *(const float4*)(pW + kt + 4);
    float4 w1a = *(const float4*)(pW + 16 * CD + kt);
    float4 w1b = *(const float4*)(pW + 16 * CD + kt + 4);
    short8 ah0, al0, ah1, al1, bh0, bl0, bh1, bl1;
    split8(a0a, a0b, &ah0, &al0);
    split8(a1a, a1b, &ah1, &al1);
    split8(w0a, w0b, &bh0, &bl0);
    split8(w1a, w1b, &bh1, &bl1);
    acc[0][0] = __builtin_amdgcn_mfma_f32_16x16x32_bf16(ah0, bh0, acc[0][0], 0, 0, 0);
    acc[0][1] = __builtin_amdgcn_mfma_f32_16x16x32_bf16(ah0, bh1, acc[0][1], 0, 0, 0);
    acc[1][0] = __builtin_amdgcn_mfma_f32_16x16x32_bf16(ah1, bh0, acc[1][0], 0, 0, 0);
    acc[1][1] = __builtin_amdgcn_mfma_f32_16x16x32_bf16(ah1, bh1, acc[1][1], 0, 0, 0);
    acc[0][0] = __builtin_amdgcn_mfma_f32_16x16x32_bf16(ah0, bl0, acc[0][0], 0, 0, 0);
    acc[0][1] = __builtin_amdgcn_mfma_f32_16x16x32_bf16(ah0, bl1, acc[0][1], 0, 0, 0);
    acc[1][0] = __builtin_amdgcn_mfma_f32_16x16x32_bf16(ah1, bl0, acc[1][0], 0, 0, 0);
    acc[1][1] = __builtin_amdgcn_mfma_f32_16x16x32_bf16(ah1, bl1, acc[1][1], 0, 0, 0);
    acc[0][0] = __builtin_amdgcn_mfma_f32_16x16x32_bf16(al0, bh0, acc[0][0], 0, 0, 0);
    acc[0][1] = __builtin_amdgcn_mfma_f32_16x16x32_bf16(al0, bh1, acc[0][1], 0, 0, 0);
    acc[1][0] = __builtin_amdgcn_mfma_f32_16x16x32_bf16(al1, bh0, acc[1][0], 0, 0, 0);
    acc[1][1] = __builtin_amdgcn_mfma_f32_16x16x32_bf16(al1, bh1, acc[1][1], 0, 0, 0);
  }
  const float K2L = 2.8853900817779268f;  // 2*log2(e)
  int b = m0 >> 9;
  int xq = (m0 & 511) + wm * 32 + q * 4;
#pragma unroll
  for (int mi = 0; mi < 2; mi++) {
#pragma unroll
    for (int ni = 0; ni < 2; ni++) {
      int h = n0 + wn * 32 + ni * 16 + ml;
      float bb = bias[h];
      f32x4 a = acc[mi][ni];
      float4 o = {fast_exp2(K2L * (a[0] + bb)), fast_exp2(K2L * (a[1] + bb)),
                  fast_exp2(K2L * (a[2] + bb)), fast_exp2(K2L * (a[3] + bb))};
      *(float4*)(ET + ((size_t)b * CH + h) * CNX + xq + mi * 16) = o;
    }
  }
}

// scT -> P planes: scores core = proven v4; epilogue computes
// P = exp(score) and stores bf16 hi/lo planes (feeds LDS-free wsum).
__global__ __launch_bounds__(512) void scores_kernel(
    const float* __restrict__ exT, const float* __restrict__ erT,
    const float* __restrict__ v_w,
    unsigned short* __restrict__ PH, unsigned short* __restrict__ PL) {
  // layout: xs0[32*64] rs0[32*64] xs1[32*64] rs1[32*64] vsh[256]
  __shared__ float smem[4 * 2048 + 256];
  int b = blockIdx.z;
  int x0 = blockIdx.x * 64, r0 = blockIdx.y * 64;
  int tid = threadIdx.x;
  int g = tid >> 8;      // reduction group
  int t = tid & 255;
  float* xs = smem + g * 4096;   // [32][64]
  float* rs = xs + 2048;         // [32][64]
  float* vsh = smem + 8192;
  if (tid < 256) vsh[tid] = v_w[tid];
  int tx = t & 15, ty = t >> 4;  // tx -> x(4), ty -> r(4)
  int sr = t >> 4, sc = (t & 15) * 4;  // staging: 16 rows x 16 float4
  int wrot = (tid >> 6) & 7;     // 8 waves -> rotate hq by 0..7
  const float* pX = exT + (size_t)b * CH * CNX + x0 + sc;
  const float* pR = erT + (size_t)b * CH * CNR + r0 + sc;
  int hb = g * 32;
  float4 xa0 = *(const float4*)(pX + (size_t)(hb + sr) * CNX);
  float4 xa1 = *(const float4*)(pX + (size_t)(hb + sr + 16) * CNX);
  float4 ra0 = *(const float4*)(pR + (size_t)(hb + sr) * CNR);
  float4 ra1 = *(const float4*)(pR + (size_t)(hb + sr + 16) * CNR);
  float acc[4][4] = {};
  for (int hc = hb; hc < CH; hc += 64) {
    __syncthreads();
    *(float4*)&xs[sr * 64 + sc] = xa0;
    *(float4*)&xs[(sr + 16) * 64 + sc] = xa1;
    *(float4*)&rs[sr * 64 + sc] = ra0;
    *(float4*)&rs[(sr + 16) * 64 + sc] = ra1;
    __syncthreads();
    if (hc + 64 < CH) {
      xa0 = *(const float4*)(pX + (size_t)(hc + 64 + sr) * CNX);
      xa1 = *(const float4*)(pX + (size_t)(hc + 64 + sr + 16) * CNX);
      ra0 = *(const float4*)(pR + (size_t)(hc + 64 + sr) * CNR);
      ra1 = *(const float4*)(pR + (size_t)(hc + 64 + sr + 16) * CNR);
    }
#pragma unroll 2
    for (int hq = 0; hq < 8; hq++) {
      int h0 = ((hq + wrot) & 7) * 4;
      float4 vv = *(const float4*)&vsh[hc + h0];
      float4 xv0 = *(const float4*)&xs[(h0 + 0) * 64 + tx * 4];
      float4 xv1 = *(const float4*)&xs[(h0 + 1) * 64 + tx * 4];
      float4 xv2 = *(const float4*)&xs[(h0 + 2) * 64 + tx * 4];
      float4 xv3 = *(const float4*)&xs[(h0 + 3) * 64 + tx * 4];
      float4 rv0 = *(const float4*)&rs[(h0 + 0) * 64 + ty * 4];
      float4 rv1 = *(const float4*)&rs[(h0 + 1) * 64 + ty * 4];
      float4 rv2 = *(const float4*)&rs[(h0 + 2) * 64 + ty * 4];
      float4 rv3 = *(const float4*)&rs[(h0 + 3) * 64 + ty * 4];
      float xm0[4] = {xv0.x, xv0.y, xv0.z, xv0.w};
      float xm1[4] = {xv1.x, xv1.y, xv1.z, xv1.w};
      float xm2[4] = {xv2.x, xv2.y, xv2.z, xv2.w};
      float xm3[4] = {xv3.x, xv3.y, xv3.z, xv3.w};
      float rm0[4] = {rv0.x, rv0.y, rv0.z, rv0.w};
      float rm1[4] = {rv1.x, rv1.y, rv1.z, rv1.w};
      float rm2[4] = {rv2.x, rv2.y, rv2.z, rv2.w};
      float rm3[4] = {rv3.x, rv3.y, rv3.z, rv3.w};
#pragma unroll
      for (int i = 0; i < 4; i++)
#pragma unroll
        for (int j = 0; j < 4; j++) {
          float a = fmaf(rm0[i], xm0[j], 1.0f);
          float bb = fmaf(rm1[i], xm1[j], 1.0f);
          float c = fmaf(rm2[i], xm2[j], 1.0f);
          float d = fmaf(rm3[i], xm3[j], 1.0f);
          float q12 = a * bb, q34 = c * d;
          float p12 = fmaf(vv.y, a, vv.x * bb);
          float p34 = fmaf(vv.w, c, vv.z * d);
          float num = fmaf(p34, q12, p12 * q34);
          acc[i][j] = fmaf(num, fast_rcp(q12 * q34), acc[i][j]);
        }
    }
  }
  // merge the two h-partials (reuse smem[0..4096) after barrier)
  __syncthreads();
  float* mg = smem;
  if (g == 1) {
#pragma unroll
    for (int i = 0; i < 4; i++)
#pragma unroll
      for (int j = 0; j < 4; j++)
        mg[t + 256 * (i * 4 + j)] = acc[i][j];
  }
  __syncthreads();
  if (g == 0) {
    const float L2E = 1.4426950408889634f;
    size_t ro = ((size_t)b * CNR + r0 + ty * 4) * CNX + x0 + tx * 4;
#pragma unroll
    for (int i = 0; i < 4; i++) {
      float4 sv = {-2.0f * (acc[i][0] + mg[t + 256 * (i * 4 + 0)]),
                   -2.0f * (acc[i][1] + mg[t + 256 * (i * 4 + 1)]),
                   -2.0f * (acc[i][2] + mg[t + 256 * (i * 4 + 2)]),
                   -2.0f * (acc[i][3] + mg[t + 256 * (i * 4 + 3)])};
      float4 pv = {fast_exp2(sv.x * L2E), fast_exp2(sv.y * L2E),
                   fast_exp2(sv.z * L2E), fast_exp2(sv.w * L2E)};
      ushort4 H, L;
      split4(pv, &H, &L);
      *(ushort4*)(PH + ro + (size_t)i * CNX) = H;
      *(ushort4*)(PL + ro + (size_t)i * CNX) = L;
    }
  }
}

// X[b][x][d] fp32 -> XT hi/lo bf16 planes [b][d][x] (runs after scores,
// reusing the dead exT region). 64x x 64d tile, grid (8,4,8), block 256.
__global__ __launch_bounds__(256) void xt_kernel(
    const float* __restrict__ X,
    unsigned short* __restrict__ XH, unsigned short* __restrict__ XL) {
  __shared__ float T[64][68];
  int b = blockIdx.z;
  int x0 = blockIdx.x * 64, d0 = blockIdx.y * 64;
  int t = threadIdx.x;
  int xl = t >> 4, c4 = (t & 15) * 4;
#pragma unroll
  for (int p = 0; p < 4; p++) {
    float4 v = *(const float4*)(X + ((size_t)(b * 512 + x0 + xl + p * 16)) * CD + d0 + c4);
    *(float4*)&T[xl + p * 16][c4] = v;
  }
  __syncthreads();
  int dl = t & 63, xseg = t >> 6;
  unsigned h[8], l[8];
#pragma unroll
  for (int i = 0; i < 8; i++) {
    float f0 = T[xseg * 16 + 2 * i][dl];
    float f1 = T[xseg * 16 + 2 * i + 1][dl];
    unsigned u0 = __float_as_uint(f0), u1 = __float_as_uint(f1);
    h[i] = (u0 >> 16) | (u1 & 0xFFFF0000u);
    float r0 = f0 - __uint_as_float(u0 & 0xFFFF0000u);
    float r1 = f1 - __uint_as_float(u1 & 0xFFFF0000u);
    l[i] = (__float_as_uint(r0) >> 16) | (__float_as_uint(r1) & 0xFFFF0000u);
  }
  size_t o = ((size_t)(b * 256 + d0 + dl)) * CNX + x0 + xseg * 16;
  uint4 h0 = {h[0], h[1], h[2], h[3]};
  uint4 h1 = {h[4], h[5], h[6], h[7]};
  uint4 l0 = {l[0], l[1], l[2], l[3]};
  uint4 l1 = {l[4], l[5], l[6], l[7]};
  *(uint4*)(XH + o) = h0;
  *(uint4*)(XH + o + 8) = h1;
  *(uint4*)(XL + o) = l0;
  *(uint4*)(XL + o + 8) = l1;
}

// Fused softmax + weighted sum, LDS-FREE: P (bf16 hi/lo planes from scores)
// and XT (bf16 hi/lo planes from xt_kernel) fragments load directly from
// global, fully-coalesced 64B lines, L2-resident. No barriers in K loop;
// denominator from in-register bf16 unpack on wave 0.
// 32(r) x 64(d) tile, grid (16,4,8)=512 blocks, block 256 = 4 waves.
__global__ __launch_bounds__(256) void wsum_mfma(
    const unsigned short* __restrict__ PH, const unsigned short* __restrict__ PL,
    const unsigned short* __restrict__ XH, const unsigned short* __restrict__ XL,
    float* __restrict__ out) {
  __shared__ float dn[32];
  int b = blockIdx.z;
  int r0 = blockIdx.x * 32, d0 = blockIdx.y * 64;
  int tid = threadIdx.x;
  int lane = tid & 63, wn = tid >> 6;  // wn = d-quarter
  int q = lane >> 4, ml = lane & 15;
  const unsigned short* pPh = PH + ((size_t)b * CNR + r0 + ml) * CNX + q * 8;
  const unsigned short* pPl = PL + ((size_t)b * CNR + r0 + ml) * CNX + q * 8;
  const unsigned short* pXh = XH + ((size_t)b * CD + d0 + wn * 16 + ml) * CNX + q * 8;
  const unsigned short* pXl = XL + ((size_t)b * CD + d0 + wn * 16 + ml) * CNX + q * 8;
  f32x4 acc0 = {}, acc1 = {};
  float d0s = 0.0f, d1s = 0.0f;
  for (int s = 0; s < 16; s++) {
    int kt = s * 32;
    short8 ah0 = *(const short8*)(pPh + kt);
    short8 ah1 = *(const short8*)(pPh + kt + 16 * CNX);
    short8 al0 = *(const short8*)(pPl + kt);
    short8 al1 = *(const short8*)(pPl + kt + 16 * CNX);
    short8 bh = *(const short8*)(pXh + kt);
    short8 bl = *(const short8*)(pXl + kt);
    acc0 = __builtin_amdgcn_mfma_f32_16x16x32_bf16(ah0, bh, acc0, 0, 0, 0);
    acc1 = __builtin_amdgcn_mfma_f32_16x16x32_bf16(ah1, bh, acc1, 0, 0, 0);
    acc0 = __builtin_amdgcn_mfma_f32_16x16x32_bf16(ah0, bl, acc0, 0, 0, 0);
    acc1 = __builtin_amdgcn_mfma_f32_16x16x32_bf16(ah1, bl, acc1, 0, 0, 0);
    acc0 = __builtin_amdgcn_mfma_f32_16x16x32_bf16(al0, bh, acc0, 0, 0, 0);
    acc1 = __builtin_amdgcn_mfma_f32_16x16x32_bf16(al1, bh, acc1, 0, 0, 0);
    if (wn == 0) {
#pragma unroll
      for (int j = 0; j < 8; j++) {
        float p0 = __uint_as_float(((unsigned)(unsigned short)ah0[j]) << 16) +
                   __uint_as_float(((unsigned)(unsigned short)al0[j]) << 16);
        float p1 = __uint_as_float(((unsigned)(unsigned short)ah1[j]) << 16) +
                   __uint_as_float(((unsigned)(unsigned short)al1[j]) << 16);
        d0s += p0;
        d1s += p1;
      }
    }
  }
  if (wn == 0) {
    d0s += __shfl_xor(d0s, 16, 64);
    d0s += __shfl_xor(d0s, 32, 64);
    d1s += __shfl_xor(d1s, 16, 64);
    d1s += __shfl_xor(d1s, 32, 64);
    if (lane < 16) {
      dn[lane] = d0s;
      dn[16 + lane] = d1s;
    }
  }
  __syncthreads();
  int col = d0 + wn * 16 + ml;
  float* pO = out + ((size_t)b * CNR + r0) * CD + col;
#pragma unroll
  for (int j = 0; j < 4; j++) {
    int row = q * 4 + j;
    pO[(size_t)row * CD] = acc0[j] * fast_rcp(dn[row]);
  }
#pragma unroll
  for (int j = 0; j < 4; j++) {
    int row = 16 + q * 4 + j;
    pO[(size_t)row * CD] = acc1[j] * fast_rcp(dn[row]);
  }
}

extern "C" void kernel_launch(void* const* d_in, const int* in_sizes, int n_in,
                              void* d_out, int out_size, void* d_ws, size_t ws_size,
                              hipStream_t stream) {
  const float* X     = (const float*)d_in[0];
  const float* ref   = (const float*)d_in[1];
  const float* W_X   = (const float*)d_in[2];
  const float* b_X   = (const float*)d_in[3];
  const float* W_ref = (const float*)d_in[4];
  const float* b_ref = (const float*)d_in[5];
  const float* v_w   = (const float*)d_in[6];
  float* out = (float*)d_out;
  float* ws  = (float*)d_ws;

  // ws layout (16 MB total):
  //   [0 : 4MB)   exT fp32 [8][256][512]   -- dead after scores; then
  //               XThi (2MB) + XTlo (2MB) bf16 [8][256][512]
  //   [4 : 8MB)   erT fp32 [8][256][512]
  //   [8 :12MB)   PH bf16-hi [8][512][512]
  //   [12:16MB)   PL bf16-lo [8][512][512]
  float* exT = ws;
  float* erT = ws + 1048576;
  unsigned short* PH = (unsigned short*)(ws + 2097152);
  unsigned short* PL = PH + 2097152;
  unsigned short* XH = (unsigned short*)ws;
  unsigned short* XL = XH + 1048576;

  proj_mfma<<<dim3(64, 4, 2), 256, 0, stream>>>(X, ref, W_X, W_ref, b_X, b_ref, exT, erT);
  scores_kernel<<<dim3(8, 8, 8), 512, 0, stream>>>(exT, erT, v_w, PH, PL);
  xt_kernel<<<dim3(8, 4, 8), 256, 0, stream>>>(X, XH, XL);
  wsum_mfma<<<dim3(16, 4, 8), 256, 0, stream>>>(PH, PL, XH, XL, out);
}

// Round 12
// 142.038 us; speedup vs baseline: 1.1063x; 1.1063x over previous
//
#include <hip/hip_runtime.h>
#include <math.h>

#define CB 8
#define CNX 512
#define CNR 512
#define CD 256
#define CH 256

typedef __attribute__((ext_vector_type(8))) short short8;
typedef __attribute__((ext_vector_type(4))) float f32x4;
typedef __attribute__((ext_vector_type(4))) unsigned int uint32x4;

__device__ __forceinline__ float fast_rcp(float x) {
#if __has_builtin(__builtin_amdgcn_rcpf)
  return __builtin_amdgcn_rcpf(x);
#else
  return 1.0f / x;
#endif
}
__device__ __forceinline__ float fast_exp2(float x) {
#if __has_builtin(__builtin_amdgcn_exp2f)
  return __builtin_amdgcn_exp2f(x);
#else
  return exp2f(x);
#endif
}

// Split 8 consecutive fp32 (two float4) into bf16 hi / lo short8 frags,
// fully in registers (bit_cast, no address-taken locals -> no scratch).
__device__ __forceinline__ void split8(float4 u, float4 v, short8* H, short8* L) {
  unsigned ux = __float_as_uint(u.x), uy = __float_as_uint(u.y);
  unsigned uz = __float_as_uint(u.z), uw = __float_as_uint(u.w);
  unsigned vx = __float_as_uint(v.x), vy = __float_as_uint(v.y);
  unsigned vz = __float_as_uint(v.z), vw = __float_as_uint(v.w);
  uint32x4 Hp = {(ux >> 16) | (uy & 0xFFFF0000u),
                 (uz >> 16) | (uw & 0xFFFF0000u),
                 (vx >> 16) | (vy & 0xFFFF0000u),
                 (vz >> 16) | (vw & 0xFFFF0000u)};
  float rux = u.x - __uint_as_float(ux & 0xFFFF0000u);
  float ruy = u.y - __uint_as_float(uy & 0xFFFF0000u);
  float ruz = u.z - __uint_as_float(uz & 0xFFFF0000u);
  float ruw = u.w - __uint_as_float(uw & 0xFFFF0000u);
  float rvx = v.x - __uint_as_float(vx & 0xFFFF0000u);
  float rvy = v.y - __uint_as_float(vy & 0xFFFF0000u);
  float rvz = v.z - __uint_as_float(vz & 0xFFFF0000u);
  float rvw = v.w - __uint_as_float(vw & 0xFFFF0000u);
  uint32x4 Lp = {(__float_as_uint(rux) >> 16) | (__float_as_uint(ruy) & 0xFFFF0000u),
                 (__float_as_uint(ruz) >> 16) | (__float_as_uint(ruw) & 0xFFFF0000u),
                 (__float_as_uint(rvx) >> 16) | (__float_as_uint(rvy) & 0xFFFF0000u),
                 (__float_as_uint(rvz) >> 16) | (__float_as_uint(rvw) & 0xFFFF0000u)};
  *H = __builtin_bit_cast(short8, Hp);
  *L = __builtin_bit_cast(short8, Lp);
}

// Split float4 -> bf16 hi ushort4 + lo ushort4 (truncation + residual).
__device__ __forceinline__ void split4(float4 v, ushort4* H, ushort4* L) {
  unsigned ux = __float_as_uint(v.x), uy = __float_as_uint(v.y);
  unsigned uz = __float_as_uint(v.z), uw = __float_as_uint(v.w);
  H->x = (unsigned short)(ux >> 16);
  H->y = (unsigned short)(uy >> 16);
  H->z = (unsigned short)(uz >> 16);
  H->w = (unsigned short)(uw >> 16);
  float rx = v.x - __uint_as_float(ux & 0xFFFF0000u);
  float ry = v.y - __uint_as_float(uy & 0xFFFF0000u);
  float rz = v.z - __uint_as_float(uz & 0xFFFF0000u);
  float rw = v.w - __uint_as_float(uw & 0xFFFF0000u);
  L->x = (unsigned short)(__float_as_uint(rx) >> 16);
  L->y = (unsigned short)(__float_as_uint(ry) >> 16);
  L->z = (unsigned short)(__float_as_uint(rz) >> 16);
  L->w = (unsigned short)(__float_as_uint(rw) >> 16);
}

// Fused projections via split-bf16 MFMA, LDS-FREE with d1 REGISTER PREFETCH:
// next K-step's 8 float4 loads issue before the current step's split+MFMA
// chain (~190cyc) -> L2 latency (~200cyc) hidden. No barriers, no LDS.
// frags: row = lane&15, k = q*8+j -> contiguous 16B/lane, 64B lines.
// 64(m) x 64(h) tile, K-step 32, grid (64,4,2), block 256 = 4 waves.
__global__ __launch_bounds__(256) void proj_mfma(
    const float* __restrict__ A0, const float* __restrict__ A1,
    const float* __restrict__ W0, const float* __restrict__ W1,
    const float* __restrict__ bias0, const float* __restrict__ bias1,
    float* __restrict__ E0, float* __restrict__ E1) {
  int z = blockIdx.z;
  const float* A = z ? A1 : A0;
  const float* W = z ? W1 : W0;
  const float* bias = z ? bias1 : bias0;
  float* ET = z ? E1 : E0;
  int m0 = blockIdx.x * 64, n0 = blockIdx.y * 64;
  int tid = threadIdx.x;
  int lane = tid & 63, w = tid >> 6;
  int wm = w >> 1, wn = w & 1;  // wave quadrant: m-half, n-half
  int q = lane >> 4, ml = lane & 15;
  const float* pA = A + (size_t)(m0 + wm * 32 + ml) * CD + q * 8;
  const float* pW = W + (size_t)(n0 + wn * 32 + ml) * CD + q * 8;
  f32x4 acc[2][2] = {};
  float4 ca0 = *(const float4*)(pA);
  float4 ca1 = *(const float4*)(pA + 4);
  float4 cb0 = *(const float4*)(pA + 16 * CD);
  float4 cb1 = *(const float4*)(pA + 16 * CD + 4);
  float4 cw0 = *(const float4*)(pW);
  float4 cw1 = *(const float4*)(pW + 4);
  float4 cx0 = *(const float4*)(pW + 16 * CD);
  float4 cx1 = *(const float4*)(pW + 16 * CD + 4);
  for (int s = 0; s < 8; s++) {
    float4 na0, na1, nb0, nb1, nw0, nw1, nx0, nx1;
    if (s < 7) {
      int kt = (s + 1) * 32;
      na0 = *(const float4*)(pA + kt);
      na1 = *(const float4*)(pA + kt + 4);
      nb0 = *(const float4*)(pA + 16 * CD + kt);
      nb1 = *(const float4*)(pA + 16 * CD + kt + 4);
      nw0 = *(const float4*)(pW + kt);
      nw1 = *(const float4*)(pW + kt + 4);
      nx0 = *(const float4*)(pW + 16 * CD + kt);
      nx1 = *(const float4*)(pW + 16 * CD + kt + 4);
    }
    short8 ah0, al0, ah1, al1, bh0, bl0, bh1, bl1;
    split8(ca0, ca1, &ah0, &al0);
    split8(cb0, cb1, &ah1, &al1);
    split8(cw0, cw1, &bh0, &bl0);
    split8(cx0, cx1, &bh1, &bl1);
    acc[0][0] = __builtin_amdgcn_mfma_f32_16x16x32_bf16(ah0, bh0, acc[0][0], 0, 0, 0);
    acc[0][1] = __builtin_amdgcn_mfma_f32_16x16x32_bf16(ah0, bh1, acc[0][1], 0, 0, 0);
    acc[1][0] = __builtin_amdgcn_mfma_f32_16x16x32_bf16(ah1, bh0, acc[1][0], 0, 0, 0);
    acc[1][1] = __builtin_amdgcn_mfma_f32_16x16x32_bf16(ah1, bh1, acc[1][1], 0, 0, 0);
    acc[0][0] = __builtin_amdgcn_mfma_f32_16x16x32_bf16(ah0, bl0, acc[0][0], 0, 0, 0);
    acc[0][1] = __builtin_amdgcn_mfma_f32_16x16x32_bf16(ah0, bl1, acc[0][1], 0, 0, 0);
    acc[1][0] = __builtin_amdgcn_mfma_f32_16x16x32_bf16(ah1, bl0, acc[1][0], 0, 0, 0);
    acc[1][1] = __builtin_amdgcn_mfma_f32_16x16x32_bf16(ah1, bl1, acc[1][1], 0, 0, 0);
    acc[0][0] = __builtin_amdgcn_mfma_f32_16x16x32_bf16(al0, bh0, acc[0][0], 0, 0, 0);
    acc[0][1] = __builtin_amdgcn_mfma_f32_16x16x32_bf16(al0, bh1, acc[0][1], 0, 0, 0);
    acc[1][0] = __builtin_amdgcn_mfma_f32_16x16x32_bf16(al1, bh0, acc[1][0], 0, 0, 0);
    acc[1][1] = __builtin_amdgcn_mfma_f32_16x16x32_bf16(al1, bh1, acc[1][1], 0, 0, 0);
    if (s < 7) {
      ca0 = na0; ca1 = na1; cb0 = nb0; cb1 = nb1;
      cw0 = nw0; cw1 = nw1; cx0 = nx0; cx1 = nx1;
    }
  }
  const float K2L = 2.8853900817779268f;  // 2*log2(e)
  int b = m0 >> 9;
  int xq = (m0 & 511) + wm * 32 + q * 4;
#pragma unroll
  for (int mi = 0; mi < 2; mi++) {
#pragma unroll
    for (int ni = 0; ni < 2; ni++) {
      int h = n0 + wn * 32 + ni * 16 + ml;
      float bb = bias[h];
      f32x4 a = acc[mi][ni];
      float4 o = {fast_exp2(K2L * (a[0] + bb)), fast_exp2(K2L * (a[1] + bb)),
                  fast_exp2(K2L * (a[2] + bb)), fast_exp2(K2L * (a[3] + bb))};
      *(float4*)(ET + ((size_t)b * CH + h) * CNX + xq + mi * 16) = o;
    }
  }
}

// scT[b][r][x] = -2 * sum_h v_w[h] / (exT[b][h][x]*erT[b][h][r] + 1)
// v4 (proven 51.4-51.9us): 64(x) x 64(r) tile, grid (8,8,8)=512 blocks,
// block 512 (two 256-thread groups h-splitting), 4x4 microtile,
// LDS partial-merge, per-wave hq-rotation. fp32 scT output.
__global__ __launch_bounds__(512) void scores_kernel(
    const float* __restrict__ exT, const float* __restrict__ erT,
    const float* __restrict__ v_w, float* __restrict__ scT) {
  // layout: xs0[32*64] rs0[32*64] xs1[32*64] rs1[32*64] vsh[256]
  __shared__ float smem[4 * 2048 + 256];
  int b = blockIdx.z;
  int x0 = blockIdx.x * 64, r0 = blockIdx.y * 64;
  int tid = threadIdx.x;
  int g = tid >> 8;      // reduction group
  int t = tid & 255;
  float* xs = smem + g * 4096;   // [32][64]
  float* rs = xs + 2048;         // [32][64]
  float* vsh = smem + 8192;
  if (tid < 256) vsh[tid] = v_w[tid];
  int tx = t & 15, ty = t >> 4;  // tx -> x(4), ty -> r(4)
  int sr = t >> 4, sc = (t & 15) * 4;  // staging: 16 rows x 16 float4
  int wrot = (tid >> 6) & 7;     // 8 waves -> rotate hq by 0..7
  const float* pX = exT + (size_t)b * CH * CNX + x0 + sc;
  const float* pR = erT + (size_t)b * CH * CNR + r0 + sc;
  int hb = g * 32;
  float4 xa0 = *(const float4*)(pX + (size_t)(hb + sr) * CNX);
  float4 xa1 = *(const float4*)(pX + (size_t)(hb + sr + 16) * CNX);
  float4 ra0 = *(const float4*)(pR + (size_t)(hb + sr) * CNR);
  float4 ra1 = *(const float4*)(pR + (size_t)(hb + sr + 16) * CNR);
  float acc[4][4] = {};
  for (int hc = hb; hc < CH; hc += 64) {
    __syncthreads();
    *(float4*)&xs[sr * 64 + sc] = xa0;
    *(float4*)&xs[(sr + 16) * 64 + sc] = xa1;
    *(float4*)&rs[sr * 64 + sc] = ra0;
    *(float4*)&rs[(sr + 16) * 64 + sc] = ra1;
    __syncthreads();
    if (hc + 64 < CH) {
      xa0 = *(const float4*)(pX + (size_t)(hc + 64 + sr) * CNX);
      xa1 = *(const float4*)(pX + (size_t)(hc + 64 + sr + 16) * CNX);
      ra0 = *(const float4*)(pR + (size_t)(hc + 64 + sr) * CNR);
      ra1 = *(const float4*)(pR + (size_t)(hc + 64 + sr + 16) * CNR);
    }
#pragma unroll 2
    for (int hq = 0; hq < 8; hq++) {
      int h0 = ((hq + wrot) & 7) * 4;
      float4 vv = *(const float4*)&vsh[hc + h0];
      float4 xv0 = *(const float4*)&xs[(h0 + 0) * 64 + tx * 4];
      float4 xv1 = *(const float4*)&xs[(h0 + 1) * 64 + tx * 4];
      float4 xv2 = *(const float4*)&xs[(h0 + 2) * 64 + tx * 4];
      float4 xv3 = *(const float4*)&xs[(h0 + 3) * 64 + tx * 4];
      float4 rv0 = *(const float4*)&rs[(h0 + 0) * 64 + ty * 4];
      float4 rv1 = *(const float4*)&rs[(h0 + 1) * 64 + ty * 4];
      float4 rv2 = *(const float4*)&rs[(h0 + 2) * 64 + ty * 4];
      float4 rv3 = *(const float4*)&rs[(h0 + 3) * 64 + ty * 4];
      float xm0[4] = {xv0.x, xv0.y, xv0.z, xv0.w};
      float xm1[4] = {xv1.x, xv1.y, xv1.z, xv1.w};
      float xm2[4] = {xv2.x, xv2.y, xv2.z, xv2.w};
      float xm3[4] = {xv3.x, xv3.y, xv3.z, xv3.w};
      float rm0[4] = {rv0.x, rv0.y, rv0.z, rv0.w};
      float rm1[4] = {rv1.x, rv1.y, rv1.z, rv1.w};
      float rm2[4] = {rv2.x, rv2.y, rv2.z, rv2.w};
      float rm3[4] = {rv3.x, rv3.y, rv3.z, rv3.w};
#pragma unroll
      for (int i = 0; i < 4; i++)
#pragma unroll
        for (int j = 0; j < 4; j++) {
          float a = fmaf(rm0[i], xm0[j], 1.0f);
          float bb = fmaf(rm1[i], xm1[j], 1.0f);
          float c = fmaf(rm2[i], xm2[j], 1.0f);
          float d = fmaf(rm3[i], xm3[j], 1.0f);
          float q12 = a * bb, q34 = c * d;
          float p12 = fmaf(vv.y, a, vv.x * bb);
          float p34 = fmaf(vv.w, c, vv.z * d);
          float num = fmaf(p34, q12, p12 * q34);
          acc[i][j] = fmaf(num, fast_rcp(q12 * q34), acc[i][j]);
        }
    }
  }
  // merge the two h-partials (reuse smem[0..4096) after barrier)
  __syncthreads();
  float* mg = smem;
  if (g == 1) {
#pragma unroll
    for (int i = 0; i < 4; i++)
#pragma unroll
      for (int j = 0; j < 4; j++)
        mg[t + 256 * (i * 4 + j)] = acc[i][j];
  }
  __syncthreads();
  if (g == 0) {
    float* pO = scT + ((size_t)b * CNR + r0 + ty * 4) * CNX + x0 + tx * 4;
#pragma unroll
    for (int i = 0; i < 4; i++) {
      float4 o = {-2.0f * (acc[i][0] + mg[t + 256 * (i * 4 + 0)]),
                  -2.0f * (acc[i][1] + mg[t + 256 * (i * 4 + 1)]),
                  -2.0f * (acc[i][2] + mg[t + 256 * (i * 4 + 2)]),
                  -2.0f * (acc[i][3] + mg[t + 256 * (i * 4 + 3)])};
      *(float4*)(pO + (size_t)i * CNX) = o;
    }
  }
}

// Fused softmax + weighted sum via split-bf16 MFMA (r6 champion version).
// out[b][r][d] = sum_x P[r][x]*X[x][d] / sum_x P[r][x], P = exp(scT).
// 64(r) x 64(d) tile, K-step 32(x), grid (8,4,8)=256 blocks, block 512 =
// 8 waves (2 r-halves x 4 d-quarters), 3 mfma per frag-pair.
// LDS rows = [hi(32k) | lo(32k)] bf16 with XOR swizzle (slot ^= row&7).
__global__ __launch_bounds__(512) void wsum_mfma(
    const float* __restrict__ scT, const float* __restrict__ X,
    float* __restrict__ out) {
  // [buf][mat: P, Xt][row][64 ushort]; row = [hi 32k | lo 32k], 8 slots x 16B
  __shared__ unsigned short lds[2][2][64][64];
  __shared__ float dn[64];
  const float L2E = 1.4426950408889634f;
  int b = blockIdx.z;
  int r0 = blockIdx.x * 64, d0 = blockIdx.y * 64;
  int tid = threadIdx.x;
  int lane = tid & 63, w = tid >> 6;
  int wm = w >> 2, wn = w & 3;  // r-half (32), d-quarter (16)
  // P staging: row pr (64), 4 k per thread
  int pr = tid >> 3, pxk = (tid & 7) * 4;
  int psl = pxk >> 3, pof = pxk & 7;  // slot 0..3, offset 0 or 4
  // X staging: d-row xd (64), 4 x per thread (in-register transpose)
  int xd = tid & 63, xx = (tid >> 6) * 4;
  int xsl = xx >> 3, xof = xx & 7;
  const float* pS = scT + ((size_t)b * CNR + r0 + pr) * CNX + pxk;
  const float* pX = X + ((size_t)b * CNX + xx) * CD + d0 + xd;
  f32x4 acc0 = {}, acc1 = {};
  float dsum = 0.0f;
  float4 sv = *(const float4*)(pS);
  float4 xv = {pX[0], pX[CD], pX[2 * CD], pX[3 * CD]};
  {
    float4 ev = {fast_exp2(sv.x * L2E), fast_exp2(sv.y * L2E),
                 fast_exp2(sv.z * L2E), fast_exp2(sv.w * L2E)};
    dsum += (ev.x + ev.y) + (ev.z + ev.w);
    ushort4 H, L;
    split4(ev, &H, &L);
    unsigned short* rp = &lds[0][0][pr][0];
    *(ushort4*)(rp + ((psl ^ (pr & 7)) << 3) + pof) = H;
    *(ushort4*)(rp + (((psl + 4) ^ (pr & 7)) << 3) + pof) = L;
    split4(xv, &H, &L);
    unsigned short* rx = &lds[0][1][xd][0];
    *(ushort4*)(rx + ((xsl ^ (xd & 7)) << 3) + xof) = H;
    *(ushort4*)(rx + (((xsl + 4) ^ (xd & 7)) << 3) + xof) = L;
  }
  int q = lane >> 4;            // k-slot 0..3
  int mr0 = wm * 32 + (lane & 15);
  int mr1 = mr0 + 16;
  int nr = wn * 16 + (lane & 15);
  for (int s = 0; s < 16; s++) {
    __syncthreads();
    if (s < 15) {
      int kt = (s + 1) * 32;
      sv = *(const float4*)(pS + kt);
      xv.x = pX[(size_t)(kt + 0) * CD];
      xv.y = pX[(size_t)(kt + 1) * CD];
      xv.z = pX[(size_t)(kt + 2) * CD];
      xv.w = pX[(size_t)(kt + 3) * CD];
    }
    int cur = s & 1;
    const unsigned short* Pt = &lds[cur][0][0][0];
    const unsigned short* Xt = &lds[cur][1][0][0];
    short8 ah0 = *(const short8*)(Pt + mr0 * 64 + ((q ^ (mr0 & 7)) << 3));
    short8 al0 = *(const short8*)(Pt + mr0 * 64 + (((q + 4) ^ (mr0 & 7)) << 3));
    short8 ah1 = *(const short8*)(Pt + mr1 * 64 + ((q ^ (mr1 & 7)) << 3));
    short8 al1 = *(const short8*)(Pt + mr1 * 64 + (((q + 4) ^ (mr1 & 7)) << 3));
    short8 bh = *(const short8*)(Xt + nr * 64 + ((q ^ (nr & 7)) << 3));
    short8 bl = *(const short8*)(Xt + nr * 64 + (((q + 4) ^ (nr & 7)) << 3));
    acc0 = __builtin_amdgcn_mfma_f32_16x16x32_bf16(ah0, bh, acc0, 0, 0, 0);
    acc1 = __builtin_amdgcn_mfma_f32_16x16x32_bf16(ah1, bh, acc1, 0, 0, 0);
    acc0 = __builtin_amdgcn_mfma_f32_16x16x32_bf16(ah0, bl, acc0, 0, 0, 0);
    acc1 = __builtin_amdgcn_mfma_f32_16x16x32_bf16(ah1, bl, acc1, 0, 0, 0);
    acc0 = __builtin_amdgcn_mfma_f32_16x16x32_bf16(al0, bh, acc0, 0, 0, 0);
    acc1 = __builtin_amdgcn_mfma_f32_16x16x32_bf16(al1, bh, acc1, 0, 0, 0);
    if (s < 15) {
      int nxt = cur ^ 1;
      float4 ev = {fast_exp2(sv.x * L2E), fast_exp2(sv.y * L2E),
                   fast_exp2(sv.z * L2E), fast_exp2(sv.w * L2E)};
      dsum += (ev.x + ev.y) + (ev.z + ev.w);
      ushort4 H, L;
      split4(ev, &H, &L);
      unsigned short* rp = &lds[nxt][0][pr][0];
      *(ushort4*)(rp + ((psl ^ (pr & 7)) << 3) + pof) = H;
      *(ushort4*)(rp + (((psl + 4) ^ (pr & 7)) << 3) + pof) = L;
      split4(xv, &H, &L);
      unsigned short* rx = &lds[nxt][1][xd][0];
      *(ushort4*)(rx + ((xsl ^ (xd & 7)) << 3) + xof) = H;
      *(ushort4*)(rx + (((xsl + 4) ^ (xd & 7)) << 3) + xof) = L;
    }
  }
  // denominator: 8 threads (tid&7) share row pr
  dsum += __shfl_xor(dsum, 1, 64);
  dsum += __shfl_xor(dsum, 2, 64);
  dsum += __shfl_xor(dsum, 4, 64);
  if ((tid & 7) == 0) dn[pr] = dsum;
  __syncthreads();
  int col = d0 + wn * 16 + (lane & 15);
  float* pO = out + ((size_t)b * CNR + r0) * CD + col;
#pragma unroll
  for (int j = 0; j < 4; j++) {
    int row = wm * 32 + q * 4 + j;
    pO[(size_t)row * CD] = acc0[j] * fast_rcp(dn[row]);
  }
#pragma unroll
  for (int j = 0; j < 4; j++) {
    int row = wm * 32 + 16 + q * 4 + j;
    pO[(size_t)row * CD] = acc1[j] * fast_rcp(dn[row]);
  }
}

extern "C" void kernel_launch(void* const* d_in, const int* in_sizes, int n_in,
                              void* d_out, int out_size, void* d_ws, size_t ws_size,
                              hipStream_t stream) {
  const float* X     = (const float*)d_in[0];
  const float* ref   = (const float*)d_in[1];
  const float* W_X   = (const float*)d_in[2];
  const float* b_X   = (const float*)d_in[3];
  const float* W_ref = (const float*)d_in[4];
  const float* b_ref = (const float*)d_in[5];
  const float* v_w   = (const float*)d_in[6];
  float* out = (float*)d_out;
  float* ws  = (float*)d_ws;

  float* exT = ws;                       // [B][H][NX] = 1,048,576 floats
  float* erT = ws + 1048576;             // [B][H][NR] = 1,048,576 floats
  float* scT = ws + 2097152;             // [B][NR][NX] = 2,097,152 floats

  proj_mfma<<<dim3(64, 4, 2), 256, 0, stream>>>(X, ref, W_X, W_ref, b_X, b_ref, exT, erT);
  scores_kernel<<<dim3(8, 8, 8), 512, 0, stream>>>(exT, erT, v_w, scT);
  wsum_mfma<<<dim3(8, 4, 8), 512, 0, stream>>>(scT, X, out);
}

// Round 13
// 137.662 us; speedup vs baseline: 1.1415x; 1.0318x over previous
//
#include <hip/hip_runtime.h>
#include <math.h>

#define CB 8
#define CNX 512
#define CNR 512
#define CD 256
#define CH 256

typedef __attribute__((ext_vector_type(8))) short short8;
typedef __attribute__((ext_vector_type(4))) float f32x4;

__device__ __forceinline__ float fast_rcp(float x) {
#if __has_builtin(__builtin_amdgcn_rcpf)
  return __builtin_amdgcn_rcpf(x);
#else
  return 1.0f / x;
#endif
}
__device__ __forceinline__ float fast_exp2(float x) {
#if __has_builtin(__builtin_amdgcn_exp2f)
  return __builtin_amdgcn_exp2f(x);
#else
  return exp2f(x);
#endif
}

// Split a float into bf16 hi (truncation) + bf16 lo (residual, truncated),
// packing 8 consecutive k-values into uint4 hi and uint4 lo, store to LDS.
__device__ __forceinline__ void cvt_store(unsigned short* dstH,
                                          unsigned short* dstL,
                                          float4 v0, float4 v1) {
  unsigned u0x = __float_as_uint(v0.x), u0y = __float_as_uint(v0.y);
  unsigned u0z = __float_as_uint(v0.z), u0w = __float_as_uint(v0.w);
  unsigned u1x = __float_as_uint(v1.x), u1y = __float_as_uint(v1.y);
  unsigned u1z = __float_as_uint(v1.z), u1w = __float_as_uint(v1.w);
  uint4 H;
  H.x = (u0x >> 16) | (u0y & 0xFFFF0000u);
  H.y = (u0z >> 16) | (u0w & 0xFFFF0000u);
  H.z = (u1x >> 16) | (u1y & 0xFFFF0000u);
  H.w = (u1z >> 16) | (u1w & 0xFFFF0000u);
  float r0x = v0.x - __uint_as_float(u0x & 0xFFFF0000u);
  float r0y = v0.y - __uint_as_float(u0y & 0xFFFF0000u);
  float r0z = v0.z - __uint_as_float(u0z & 0xFFFF0000u);
  float r0w = v0.w - __uint_as_float(u0w & 0xFFFF0000u);
  float r1x = v1.x - __uint_as_float(u1x & 0xFFFF0000u);
  float r1y = v1.y - __uint_as_float(u1y & 0xFFFF0000u);
  float r1z = v1.z - __uint_as_float(u1z & 0xFFFF0000u);
  float r1w = v1.w - __uint_as_float(u1w & 0xFFFF0000u);
  uint4 L;
  L.x = (__float_as_uint(r0x) >> 16) | (__float_as_uint(r0y) & 0xFFFF0000u);
  L.y = (__float_as_uint(r0z) >> 16) | (__float_as_uint(r0w) & 0xFFFF0000u);
  L.z = (__float_as_uint(r1x) >> 16) | (__float_as_uint(r1y) & 0xFFFF0000u);
  L.w = (__float_as_uint(r1z) >> 16) | (__float_as_uint(r1w) & 0xFFFF0000u);
  *(uint4*)dstH = H;
  *(uint4*)dstL = L;
}

// Split float4 -> bf16 hi ushort4 + lo ushort4 (truncation + residual).
__device__ __forceinline__ void split4(float4 v, ushort4* H, ushort4* L) {
  unsigned ux = __float_as_uint(v.x), uy = __float_as_uint(v.y);
  unsigned uz = __float_as_uint(v.z), uw = __float_as_uint(v.w);
  H->x = (unsigned short)(ux >> 16);
  H->y = (unsigned short)(uy >> 16);
  H->z = (unsigned short)(uz >> 16);
  H->w = (unsigned short)(uw >> 16);
  float rx = v.x - __uint_as_float(ux & 0xFFFF0000u);
  float ry = v.y - __uint_as_float(uy & 0xFFFF0000u);
  float rz = v.z - __uint_as_float(uz & 0xFFFF0000u);
  float rw = v.w - __uint_as_float(uw & 0xFFFF0000u);
  L->x = (unsigned short)(__float_as_uint(rx) >> 16);
  L->y = (unsigned short)(__float_as_uint(ry) >> 16);
  L->z = (unsigned short)(__float_as_uint(rz) >> 16);
  L->w = (unsigned short)(__float_as_uint(rw) >> 16);
}

// Fused projections via split-bf16 MFMA (3 mfma: hi*hi + hi*lo + lo*hi).
// r6 champion version: 64x64 tile, K-step 32, LDS double-buffered.
__global__ __launch_bounds__(256) void proj_mfma(
    const float* __restrict__ A0, const float* __restrict__ A1,
    const float* __restrict__ W0, const float* __restrict__ W1,
    const float* __restrict__ bias0, const float* __restrict__ bias1,
    float* __restrict__ E0, float* __restrict__ E1) {
  // [buf][mat: Ah,Al,Wh,Wl][row][k] ; row stride 40 ushort = 80 B
  __shared__ unsigned short lds[2][4][64][40];
  const int K = CD;
  int z = blockIdx.z;
  const float* A = z ? A1 : A0;
  const float* W = z ? W1 : W0;
  const float* bias = z ? bias1 : bias0;
  float* ET = z ? E1 : E0;
  int m0 = blockIdx.x * 64, n0 = blockIdx.y * 64;
  int tid = threadIdx.x;
  int lane = tid & 63, w = tid >> 6;
  int wm = w >> 1, wn = w & 1;  // wave quadrant: m-half, n-half
  int r = tid >> 2, kq = (tid & 3) * 8;
  const float* pA = A + (size_t)(m0 + r) * K + kq;
  const float* pW = W + (size_t)(n0 + r) * K + kq;
  f32x4 acc[2][2] = {};
  float4 a0 = *(const float4*)(pA);
  float4 a1 = *(const float4*)(pA + 4);
  float4 w0 = *(const float4*)(pW);
  float4 w1 = *(const float4*)(pW + 4);
  cvt_store(&lds[0][0][r][kq], &lds[0][1][r][kq], a0, a1);
  cvt_store(&lds[0][2][r][kq], &lds[0][3][r][kq], w0, w1);
  for (int s = 0; s < 8; s++) {
    __syncthreads();
    if (s < 7) {
      int kt = (s + 1) * 32;
      a0 = *(const float4*)(pA + kt);
      a1 = *(const float4*)(pA + kt + 4);
      w0 = *(const float4*)(pW + kt);
      w1 = *(const float4*)(pW + kt + 4);
    }
    int cur = s & 1;
    int arow = wm * 32 + (lane & 15);
    int brow = wn * 32 + (lane & 15);
    int koff = (lane >> 4) * 8;
    short8 ah0 = *(const short8*)&lds[cur][0][arow][koff];
    short8 ah1 = *(const short8*)&lds[cur][0][arow + 16][koff];
    short8 al0 = *(const short8*)&lds[cur][1][arow][koff];
    short8 al1 = *(const short8*)&lds[cur][1][arow + 16][koff];
    short8 bh0 = *(const short8*)&lds[cur][2][brow][koff];
    short8 bh1 = *(const short8*)&lds[cur][2][brow + 16][koff];
    short8 bl0 = *(const short8*)&lds[cur][3][brow][koff];
    short8 bl1 = *(const short8*)&lds[cur][3][brow + 16][koff];
    acc[0][0] = __builtin_amdgcn_mfma_f32_16x16x32_bf16(ah0, bh0, acc[0][0], 0, 0, 0);
    acc[0][1] = __builtin_amdgcn_mfma_f32_16x16x32_bf16(ah0, bh1, acc[0][1], 0, 0, 0);
    acc[1][0] = __builtin_amdgcn_mfma_f32_16x16x32_bf16(ah1, bh0, acc[1][0], 0, 0, 0);
    acc[1][1] = __builtin_amdgcn_mfma_f32_16x16x32_bf16(ah1, bh1, acc[1][1], 0, 0, 0);
    acc[0][0] = __builtin_amdgcn_mfma_f32_16x16x32_bf16(ah0, bl0, acc[0][0], 0, 0, 0);
    acc[0][1] = __builtin_amdgcn_mfma_f32_16x16x32_bf16(ah0, bl1, acc[0][1], 0, 0, 0);
    acc[1][0] = __builtin_amdgcn_mfma_f32_16x16x32_bf16(ah1, bl0, acc[1][0], 0, 0, 0);
    acc[1][1] = __builtin_amdgcn_mfma_f32_16x16x32_bf16(ah1, bl1, acc[1][1], 0, 0, 0);
    acc[0][0] = __builtin_amdgcn_mfma_f32_16x16x32_bf16(al0, bh0, acc[0][0], 0, 0, 0);
    acc[0][1] = __builtin_amdgcn_mfma_f32_16x16x32_bf16(al0, bh1, acc[0][1], 0, 0, 0);
    acc[1][0] = __builtin_amdgcn_mfma_f32_16x16x32_bf16(al1, bh0, acc[1][0], 0, 0, 0);
    acc[1][1] = __builtin_amdgcn_mfma_f32_16x16x32_bf16(al1, bh1, acc[1][1], 0, 0, 0);
    if (s < 7) {
      int nxt = cur ^ 1;
      cvt_store(&lds[nxt][0][r][kq], &lds[nxt][1][r][kq], a0, a1);
      cvt_store(&lds[nxt][2][r][kq], &lds[nxt][3][r][kq], w0, w1);
    }
  }
  const float K2L = 2.8853900817779268f;  // 2*log2(e)
  int b = m0 >> 9;
  int xq = (m0 & 511) + wm * 32 + (lane >> 4) * 4;
#pragma unroll
  for (int mi = 0; mi < 2; mi++) {
#pragma unroll
    for (int ni = 0; ni < 2; ni++) {
      int h = n0 + wn * 32 + ni * 16 + (lane & 15);
      float bb = bias[h];
      f32x4 a = acc[mi][ni];
      float4 o = {fast_exp2(K2L * (a[0] + bb)), fast_exp2(K2L * (a[1] + bb)),
                  fast_exp2(K2L * (a[2] + bb)), fast_exp2(K2L * (a[3] + bb))};
      *(float4*)(ET + ((size_t)b * CH + h) * CNX + xq + mi * 16) = o;
    }
  }
}

// scT[b][r][x] = -2 * sum_h v_w[h] / (exT[b][h][x]*erT[b][h][r] + 1)
// v4 core (proven 51.4-51.9us). DIAGNOSTIC SPLIT: launched as 2 dispatches
// of z=4 (b = blockIdx.z + b0) so proj/wsum can surface in the top-5.
__global__ __launch_bounds__(512) void scores_kernel(
    const float* __restrict__ exT, const float* __restrict__ erT,
    const float* __restrict__ v_w, float* __restrict__ scT, int b0) {
  // layout: xs0[32*64] rs0[32*64] xs1[32*64] rs1[32*64] vsh[256]
  __shared__ float smem[4 * 2048 + 256];
  int b = blockIdx.z + b0;
  int x0 = blockIdx.x * 64, r0 = blockIdx.y * 64;
  int tid = threadIdx.x;
  int g = tid >> 8;      // reduction group
  int t = tid & 255;
  float* xs = smem + g * 4096;   // [32][64]
  float* rs = xs + 2048;         // [32][64]
  float* vsh = smem + 8192;
  if (tid < 256) vsh[tid] = v_w[tid];
  int tx = t & 15, ty = t >> 4;  // tx -> x(4), ty -> r(4)
  int sr = t >> 4, sc = (t & 15) * 4;  // staging: 16 rows x 16 float4
  int wrot = (tid >> 6) & 7;     // 8 waves -> rotate hq by 0..7
  const float* pX = exT + (size_t)b * CH * CNX + x0 + sc;
  const float* pR = erT + (size_t)b * CH * CNR + r0 + sc;
  int hb = g * 32;
  float4 xa0 = *(const float4*)(pX + (size_t)(hb + sr) * CNX);
  float4 xa1 = *(const float4*)(pX + (size_t)(hb + sr + 16) * CNX);
  float4 ra0 = *(const float4*)(pR + (size_t)(hb + sr) * CNR);
  float4 ra1 = *(const float4*)(pR + (size_t)(hb + sr + 16) * CNR);
  float acc[4][4] = {};
  for (int hc = hb; hc < CH; hc += 64) {
    __syncthreads();
    *(float4*)&xs[sr * 64 + sc] = xa0;
    *(float4*)&xs[(sr + 16) * 64 + sc] = xa1;
    *(float4*)&rs[sr * 64 + sc] = ra0;
    *(float4*)&rs[(sr + 16) * 64 + sc] = ra1;
    __syncthreads();
    if (hc + 64 < CH) {
      xa0 = *(const float4*)(pX + (size_t)(hc + 64 + sr) * CNX);
      xa1 = *(const float4*)(pX + (size_t)(hc + 64 + sr + 16) * CNX);
      ra0 = *(const float4*)(pR + (size_t)(hc + 64 + sr) * CNR);
      ra1 = *(const float4*)(pR + (size_t)(hc + 64 + sr + 16) * CNR);
    }
#pragma unroll 2
    for (int hq = 0; hq < 8; hq++) {
      int h0 = ((hq + wrot) & 7) * 4;
      float4 vv = *(const float4*)&vsh[hc + h0];
      float4 xv0 = *(const float4*)&xs[(h0 + 0) * 64 + tx * 4];
      float4 xv1 = *(const float4*)&xs[(h0 + 1) * 64 + tx * 4];
      float4 xv2 = *(const float4*)&xs[(h0 + 2) * 64 + tx * 4];
      float4 xv3 = *(const float4*)&xs[(h0 + 3) * 64 + tx * 4];
      float4 rv0 = *(const float4*)&rs[(h0 + 0) * 64 + ty * 4];
      float4 rv1 = *(const float4*)&rs[(h0 + 1) * 64 + ty * 4];
      float4 rv2 = *(const float4*)&rs[(h0 + 2) * 64 + ty * 4];
      float4 rv3 = *(const float4*)&rs[(h0 + 3) * 64 + ty * 4];
      float xm0[4] = {xv0.x, xv0.y, xv0.z, xv0.w};
      float xm1[4] = {xv1.x, xv1.y, xv1.z, xv1.w};
      float xm2[4] = {xv2.x, xv2.y, xv2.z, xv2.w};
      float xm3[4] = {xv3.x, xv3.y, xv3.z, xv3.w};
      float rm0[4] = {rv0.x, rv0.y, rv0.z, rv0.w};
      float rm1[4] = {rv1.x, rv1.y, rv1.z, rv1.w};
      float rm2[4] = {rv2.x, rv2.y, rv2.z, rv2.w};
      float rm3[4] = {rv3.x, rv3.y, rv3.z, rv3.w};
#pragma unroll
      for (int i = 0; i < 4; i++)
#pragma unroll
        for (int j = 0; j < 4; j++) {
          float a = fmaf(rm0[i], xm0[j], 1.0f);
          float bb = fmaf(rm1[i], xm1[j], 1.0f);
          float c = fmaf(rm2[i], xm2[j], 1.0f);
          float d = fmaf(rm3[i], xm3[j], 1.0f);
          float q12 = a * bb, q34 = c * d;
          float p12 = fmaf(vv.y, a, vv.x * bb);
          float p34 = fmaf(vv.w, c, vv.z * d);
          float num = fmaf(p34, q12, p12 * q34);
          acc[i][j] = fmaf(num, fast_rcp(q12 * q34), acc[i][j]);
        }
    }
  }
  // merge the two h-partials (reuse smem[0..4096) after barrier)
  __syncthreads();
  float* mg = smem;
  if (g == 1) {
#pragma unroll
    for (int i = 0; i < 4; i++)
#pragma unroll
      for (int j = 0; j < 4; j++)
        mg[t + 256 * (i * 4 + j)] = acc[i][j];
  }
  __syncthreads();
  if (g == 0) {
    float* pO = scT + ((size_t)b * CNR + r0 + ty * 4) * CNX + x0 + tx * 4;
#pragma unroll
    for (int i = 0; i < 4; i++) {
      float4 o = {-2.0f * (acc[i][0] + mg[t + 256 * (i * 4 + 0)]),
                  -2.0f * (acc[i][1] + mg[t + 256 * (i * 4 + 1)]),
                  -2.0f * (acc[i][2] + mg[t + 256 * (i * 4 + 2)]),
                  -2.0f * (acc[i][3] + mg[t + 256 * (i * 4 + 3)])};
      *(float4*)(pO + (size_t)i * CNX) = o;
    }
  }
}

// Fused softmax + weighted sum via split-bf16 MFMA (r6 champion version).
// 64(r) x 64(d) tile, K-step 32(x), grid (8,4,8)=256 blocks, block 512.
__global__ __launch_bounds__(512) void wsum_mfma(
    const float* __restrict__ scT, const float* __restrict__ X,
    float* __restrict__ out) {
  // [buf][mat: P, Xt][row][64 ushort]; row = [hi 32k | lo 32k]
  __shared__ unsigned short lds[2][2][64][64];
  __shared__ float dn[64];
  const float L2E = 1.4426950408889634f;
  int b = blockIdx.z;
  int r0 = blockIdx.x * 64, d0 = blockIdx.y * 64;
  int tid = threadIdx.x;
  int lane = tid & 63, w = tid >> 6;
  int wm = w >> 2, wn = w & 3;  // r-half (32), d-quarter (16)
  int pr = tid >> 3, pxk = (tid & 7) * 4;
  int psl = pxk >> 3, pof = pxk & 7;
  int xd = tid & 63, xx = (tid >> 6) * 4;
  int xsl = xx >> 3, xof = xx & 7;
  const float* pS = scT + ((size_t)b * CNR + r0 + pr) * CNX + pxk;
  const float* pX = X + ((size_t)b * CNX + xx) * CD + d0 + xd;
  f32x4 acc0 = {}, acc1 = {};
  float dsum = 0.0f;
  float4 sv = *(const float4*)(pS);
  float4 xv = {pX[0], pX[CD], pX[2 * CD], pX[3 * CD]};
  {
    float4 ev = {fast_exp2(sv.x * L2E), fast_exp2(sv.y * L2E),
                 fast_exp2(sv.z * L2E), fast_exp2(sv.w * L2E)};
    dsum += (ev.x + ev.y) + (ev.z + ev.w);
    ushort4 H, L;
    split4(ev, &H, &L);
    unsigned short* rp = &lds[0][0][pr][0];
    *(ushort4*)(rp + ((psl ^ (pr & 7)) << 3) + pof) = H;
    *(ushort4*)(rp + (((psl + 4) ^ (pr & 7)) << 3) + pof) = L;
    split4(xv, &H, &L);
    unsigned short* rx = &lds[0][1][xd][0];
    *(ushort4*)(rx + ((xsl ^ (xd & 7)) << 3) + xof) = H;
    *(ushort4*)(rx + (((xsl + 4) ^ (xd & 7)) << 3) + xof) = L;
  }
  int q = lane >> 4;            // k-slot 0..3
  int mr0 = wm * 32 + (lane & 15);
  int mr1 = mr0 + 16;
  int nr = wn * 16 + (lane & 15);
  for (int s = 0; s < 16; s++) {
    __syncthreads();
    if (s < 15) {
      int kt = (s + 1) * 32;
      sv = *(const float4*)(pS + kt);
      xv.x = pX[(size_t)(kt + 0) * CD];
      xv.y = pX[(size_t)(kt + 1) * CD];
      xv.z = pX[(size_t)(kt + 2) * CD];
      xv.w = pX[(size_t)(kt + 3) * CD];
    }
    int cur = s & 1;
    const unsigned short* Pt = &lds[cur][0][0][0];
    const unsigned short* Xt = &lds[cur][1][0][0];
    short8 ah0 = *(const short8*)(Pt + mr0 * 64 + ((q ^ (mr0 & 7)) << 3));
    short8 al0 = *(const short8*)(Pt + mr0 * 64 + (((q + 4) ^ (mr0 & 7)) << 3));
    short8 ah1 = *(const short8*)(Pt + mr1 * 64 + ((q ^ (mr1 & 7)) << 3));
    short8 al1 = *(const short8*)(Pt + mr1 * 64 + (((q + 4) ^ (mr1 & 7)) << 3));
    short8 bh = *(const short8*)(Xt + nr * 64 + ((q ^ (nr & 7)) << 3));
    short8 bl = *(const short8*)(Xt + nr * 64 + (((q + 4) ^ (nr & 7)) << 3));
    acc0 = __builtin_amdgcn_mfma_f32_16x16x32_bf16(ah0, bh, acc0, 0, 0, 0);
    acc1 = __builtin_amdgcn_mfma_f32_16x16x32_bf16(ah1, bh, acc1, 0, 0, 0);
    acc0 = __builtin_amdgcn_mfma_f32_16x16x32_bf16(ah0, bl, acc0, 0, 0, 0);
    acc1 = __builtin_amdgcn_mfma_f32_16x16x32_bf16(ah1, bl, acc1, 0, 0, 0);
    acc0 = __builtin_amdgcn_mfma_f32_16x16x32_bf16(al0, bh, acc0, 0, 0, 0);
    acc1 = __builtin_amdgcn_mfma_f32_16x16x32_bf16(al1, bh, acc1, 0, 0, 0);
    if (s < 15) {
      int nxt = cur ^ 1;
      float4 ev = {fast_exp2(sv.x * L2E), fast_exp2(sv.y * L2E),
                   fast_exp2(sv.z * L2E), fast_exp2(sv.w * L2E)};
      dsum += (ev.x + ev.y) + (ev.z + ev.w);
      ushort4 H, L;
      split4(ev, &H, &L);
      unsigned short* rp = &lds[nxt][0][pr][0];
      *(ushort4*)(rp + ((psl ^ (pr & 7)) << 3) + pof) = H;
      *(ushort4*)(rp + (((psl + 4) ^ (pr & 7)) << 3) + pof) = L;
      split4(xv, &H, &L);
      unsigned short* rx = &lds[nxt][1][xd][0];
      *(ushort4*)(rx + ((xsl ^ (xd & 7)) << 3) + xof) = H;
      *(ushort4*)(rx + (((xsl + 4) ^ (xd & 7)) << 3) + xof) = L;
    }
  }
  // denominator: 8 threads (tid&7) share row pr
  dsum += __shfl_xor(dsum, 1, 64);
  dsum += __shfl_xor(dsum, 2, 64);
  dsum += __shfl_xor(dsum, 4, 64);
  if ((tid & 7) == 0) dn[pr] = dsum;
  __syncthreads();
  int col = d0 + wn * 16 + (lane & 15);
  float* pO = out + ((size_t)b * CNR + r0) * CD + col;
#pragma unroll
  for (int j = 0; j < 4; j++) {
    int row = wm * 32 + q * 4 + j;
    pO[(size_t)row * CD] = acc0[j] * fast_rcp(dn[row]);
  }
#pragma unroll
  for (int j = 0; j < 4; j++) {
    int row = wm * 32 + 16 + q * 4 + j;
    pO[(size_t)row * CD] = acc1[j] * fast_rcp(dn[row]);
  }
}

extern "C" void kernel_launch(void* const* d_in, const int* in_sizes, int n_in,
                              void* d_out, int out_size, void* d_ws, size_t ws_size,
                              hipStream_t stream) {
  const float* X     = (const float*)d_in[0];
  const float* ref   = (const float*)d_in[1];
  const float* W_X   = (const float*)d_in[2];
  const float* b_X   = (const float*)d_in[3];
  const float* W_ref = (const float*)d_in[4];
  const float* b_ref = (const float*)d_in[5];
  const float* v_w   = (const float*)d_in[6];
  float* out = (float*)d_out;
  float* ws  = (float*)d_ws;

  float* exT = ws;                       // [B][H][NX] = 1,048,576 floats
  float* erT = ws + 1048576;             // [B][H][NR] = 1,048,576 floats
  float* scT = ws + 2097152;             // [B][NR][NX] = 2,097,152 floats

  proj_mfma<<<dim3(64, 4, 2), 256, 0, stream>>>(X, ref, W_X, W_ref, b_X, b_ref, exT, erT);
  // diagnostic split: 2 dispatches of 256 blocks each so proj/wsum can
  // surface in the rocprof top-5 (scores is occupancy-insensitive, r1-r2)
  scores_kernel<<<dim3(8, 8, 4), 512, 0, stream>>>(exT, erT, v_w, scT, 0);
  scores_kernel<<<dim3(8, 8, 4), 512, 0, stream>>>(exT, erT, v_w, scT, 4);
  wsum_mfma<<<dim3(8, 4, 8), 512, 0, stream>>>(scT, X, out);
}

// Round 14
// 135.689 us; speedup vs baseline: 1.1581x; 1.0145x over previous
//
#include <hip/hip_runtime.h>
#include <math.h>

#define CB 8
#define CNX 512
#define CNR 512
#define CD 256
#define CH 256

typedef __attribute__((ext_vector_type(8))) short short8;
typedef __attribute__((ext_vector_type(4))) float f32x4;
typedef __attribute__((ext_vector_type(4))) unsigned int uint32x4;

__device__ __forceinline__ float fast_rcp(float x) {
#if __has_builtin(__builtin_amdgcn_rcpf)
  return __builtin_amdgcn_rcpf(x);
#else
  return 1.0f / x;
#endif
}
__device__ __forceinline__ float fast_exp2(float x) {
#if __has_builtin(__builtin_amdgcn_exp2f)
  return __builtin_amdgcn_exp2f(x);
#else
  return exp2f(x);
#endif
}

// Async global->LDS DMA, 16B per lane (dest = uniform base + lane*16).
__device__ __forceinline__ void gload_lds16(const float* g, float* l) {
  __builtin_amdgcn_global_load_lds(
      (const __attribute__((address_space(1))) unsigned int*)g,
      (__attribute__((address_space(3))) unsigned int*)l, 16, 0, 0);
}

// Split 8 consecutive fp32 (two float4) into bf16 hi / lo short8 frags,
// fully in registers (bit_cast, no address-taken locals -> no scratch).
__device__ __forceinline__ void split8(float4 u, float4 v, short8* H, short8* L) {
  unsigned ux = __float_as_uint(u.x), uy = __float_as_uint(u.y);
  unsigned uz = __float_as_uint(u.z), uw = __float_as_uint(u.w);
  unsigned vx = __float_as_uint(v.x), vy = __float_as_uint(v.y);
  unsigned vz = __float_as_uint(v.z), vw = __float_as_uint(v.w);
  uint32x4 Hp = {(ux >> 16) | (uy & 0xFFFF0000u),
                 (uz >> 16) | (uw & 0xFFFF0000u),
                 (vx >> 16) | (vy & 0xFFFF0000u),
                 (vz >> 16) | (vw & 0xFFFF0000u)};
  float rux = u.x - __uint_as_float(ux & 0xFFFF0000u);
  float ruy = u.y - __uint_as_float(uy & 0xFFFF0000u);
  float ruz = u.z - __uint_as_float(uz & 0xFFFF0000u);
  float ruw = u.w - __uint_as_float(uw & 0xFFFF0000u);
  float rvx = v.x - __uint_as_float(vx & 0xFFFF0000u);
  float rvy = v.y - __uint_as_float(vy & 0xFFFF0000u);
  float rvz = v.z - __uint_as_float(vz & 0xFFFF0000u);
  float rvw = v.w - __uint_as_float(vw & 0xFFFF0000u);
  uint32x4 Lp = {(__float_as_uint(rux) >> 16) | (__float_as_uint(ruy) & 0xFFFF0000u),
                 (__float_as_uint(ruz) >> 16) | (__float_as_uint(ruw) & 0xFFFF0000u),
                 (__float_as_uint(rvx) >> 16) | (__float_as_uint(rvy) & 0xFFFF0000u),
                 (__float_as_uint(rvz) >> 16) | (__float_as_uint(rvw) & 0xFFFF0000u)};
  *H = __builtin_bit_cast(short8, Hp);
  *L = __builtin_bit_cast(short8, Lp);
}

// Split float4 -> bf16 hi ushort4 + lo ushort4 (truncation + residual).
__device__ __forceinline__ void split4(float4 v, ushort4* H, ushort4* L) {
  unsigned ux = __float_as_uint(v.x), uy = __float_as_uint(v.y);
  unsigned uz = __float_as_uint(v.z), uw = __float_as_uint(v.w);
  H->x = (unsigned short)(ux >> 16);
  H->y = (unsigned short)(uy >> 16);
  H->z = (unsigned short)(uz >> 16);
  H->w = (unsigned short)(uw >> 16);
  float rx = v.x - __uint_as_float(ux & 0xFFFF0000u);
  float ry = v.y - __uint_as_float(uy & 0xFFFF0000u);
  float rz = v.z - __uint_as_float(uz & 0xFFFF0000u);
  float rw = v.w - __uint_as_float(uw & 0xFFFF0000u);
  L->x = (unsigned short)(__float_as_uint(rx) >> 16);
  L->y = (unsigned short)(__float_as_uint(ry) >> 16);
  L->z = (unsigned short)(__float_as_uint(rz) >> 16);
  L->w = (unsigned short)(__float_as_uint(rw) >> 16);
}

// Fused projections via split-bf16 MFMA, v4: global_load_lds DMA staging.
// fp32 A/W tiles land in LINEAR LDS [64][32] via async DMA; the bank
// swizzle is applied on the GLOBAL source address (rule: linear dest +
// inverse-swz source + swz read); bf16 hi/lo split happens in registers
// at consume. No ds_writes, no reg->LDS roundtrip; 1 barrier/K-step.
// 64(m) x 64(h) tile, K-step 32, grid (64,4,2), block 256 = 4 waves.
__global__ __launch_bounds__(256) void proj_mfma(
    const float* __restrict__ A0, const float* __restrict__ A1,
    const float* __restrict__ W0, const float* __restrict__ W1,
    const float* __restrict__ bias0, const float* __restrict__ bias1,
    float* __restrict__ E0, float* __restrict__ E1) {
  // [buf][mat: A,W][row*32+k] fp32, linear (DMA dest), 32 KB total
  __shared__ float lds[2][2][64 * 32];
  int z = blockIdx.z;
  const float* A = z ? A1 : A0;
  const float* W = z ? W1 : W0;
  const float* bias = z ? bias1 : bias0;
  float* ET = z ? E1 : E0;
  int m0 = blockIdx.x * 64, n0 = blockIdx.y * 64;
  int tid = threadIdx.x;
  int lane = tid & 63, w = tid >> 6;
  int wm = w >> 1, wn = w & 1;  // wave quadrant: m-half, n-half
  int q = lane >> 4, ml = lane & 15;
  // staging: 16 chunks (8 A + 8 W), wave w owns chunks 4w..4w+3.
  // chunk = 8 rows x 32 k = 1024 B; lane i -> row i>>3, 16B slot i&7.
  // source pre-swizzle: global slot = (i&7) ^ (row&7).
  int crow = lane >> 3, cslot = lane & 7;
  int gslot = (cslot ^ crow) << 2;  // dword offset of swizzled 16B slot
  float* dA = &lds[0][0][0];
  // per-wave chunk params (wave-uniform except lane terms)
  int c0 = w * 4;
  auto STAGE = [&](int buf, int kt) {
#pragma unroll
    for (int cc = 0; cc < 4; cc++) {
      int c = c0 + cc;
      int mat = c >> 3;
      int r8 = (c & 7) * 8;
      const float* base = mat ? W + (size_t)(n0 + r8 + crow) * CD
                              : A + (size_t)(m0 + r8 + crow) * CD;
      gload_lds16(base + kt + gslot, &lds[buf][mat][r8 * 32]);
    }
  };
  f32x4 acc[2][2] = {};
  STAGE(0, 0);
  int arow = wm * 32 + ml;
  int brow = wn * 32 + ml;
  for (int s = 0; s < 8; s++) {
    __syncthreads();  // drains vmcnt -> buf[cur] ready; prev compute done
    int cur = s & 1;
    if (s < 7) STAGE(cur ^ 1, (s + 1) * 32);
    // swizzled fp32 frag reads + in-register split
    const float* Ab0 = &lds[cur][0][arow * 32];
    const float* Ab1 = &lds[cur][0][(arow + 16) * 32];
    const float* Wb0 = &lds[cur][1][brow * 32];
    const float* Wb1 = &lds[cur][1][(brow + 16) * 32];
    int sa0 = ((2 * q) ^ (arow & 7)) * 4, sa1 = ((2 * q + 1) ^ (arow & 7)) * 4;
    int sb0 = ((2 * q) ^ (brow & 7)) * 4, sb1 = ((2 * q + 1) ^ (brow & 7)) * 4;
    float4 fa0 = *(const float4*)(Ab0 + sa0);
    float4 fa1 = *(const float4*)(Ab0 + sa1);
    float4 fb0 = *(const float4*)(Ab1 + sa0);
    float4 fb1 = *(const float4*)(Ab1 + sa1);
    float4 fw0 = *(const float4*)(Wb0 + sb0);
    float4 fw1 = *(const float4*)(Wb0 + sb1);
    float4 fx0 = *(const float4*)(Wb1 + sb0);
    float4 fx1 = *(const float4*)(Wb1 + sb1);
    short8 ah0, al0, ah1, al1, bh0, bl0, bh1, bl1;
    split8(fa0, fa1, &ah0, &al0);
    split8(fb0, fb1, &ah1, &al1);
    split8(fw0, fw1, &bh0, &bl0);
    split8(fx0, fx1, &bh1, &bl1);
    acc[0][0] = __builtin_amdgcn_mfma_f32_16x16x32_bf16(ah0, bh0, acc[0][0], 0, 0, 0);
    acc[0][1] = __builtin_amdgcn_mfma_f32_16x16x32_bf16(ah0, bh1, acc[0][1], 0, 0, 0);
    acc[1][0] = __builtin_amdgcn_mfma_f32_16x16x32_bf16(ah1, bh0, acc[1][0], 0, 0, 0);
    acc[1][1] = __builtin_amdgcn_mfma_f32_16x16x32_bf16(ah1, bh1, acc[1][1], 0, 0, 0);
    acc[0][0] = __builtin_amdgcn_mfma_f32_16x16x32_bf16(ah0, bl0, acc[0][0], 0, 0, 0);
    acc[0][1] = __builtin_amdgcn_mfma_f32_16x16x32_bf16(ah0, bl1, acc[0][1], 0, 0, 0);
    acc[1][0] = __builtin_amdgcn_mfma_f32_16x16x32_bf16(ah1, bl0, acc[1][0], 0, 0, 0);
    acc[1][1] = __builtin_amdgcn_mfma_f32_16x16x32_bf16(ah1, bl1, acc[1][1], 0, 0, 0);
    acc[0][0] = __builtin_amdgcn_mfma_f32_16x16x32_bf16(al0, bh0, acc[0][0], 0, 0, 0);
    acc[0][1] = __builtin_amdgcn_mfma_f32_16x16x32_bf16(al0, bh1, acc[0][1], 0, 0, 0);
    acc[1][0] = __builtin_amdgcn_mfma_f32_16x16x32_bf16(al1, bh0, acc[1][0], 0, 0, 0);
    acc[1][1] = __builtin_amdgcn_mfma_f32_16x16x32_bf16(al1, bh1, acc[1][1], 0, 0, 0);
  }
  (void)dA;
  const float K2L = 2.8853900817779268f;  // 2*log2(e)
  int b = m0 >> 9;
  int xq = (m0 & 511) + wm * 32 + q * 4;
#pragma unroll
  for (int mi = 0; mi < 2; mi++) {
#pragma unroll
    for (int ni = 0; ni < 2; ni++) {
      int h = n0 + wn * 32 + ni * 16 + ml;
      float bb = bias[h];
      f32x4 a = acc[mi][ni];
      float4 o = {fast_exp2(K2L * (a[0] + bb)), fast_exp2(K2L * (a[1] + bb)),
                  fast_exp2(K2L * (a[2] + bb)), fast_exp2(K2L * (a[3] + bb))};
      *(float4*)(ET + ((size_t)b * CH + h) * CNX + xq + mi * 16) = o;
    }
  }
}

// scT[b][r][x] = -2 * sum_h v_w[h] / (exT[b][h][x]*erT[b][h][r] + 1)
// v4 (proven 51.4-51.9us): 64(x) x 64(r) tile, grid (8,8,8)=512 blocks,
// block 512 (two 256-thread groups h-splitting), 4x4 microtile.
__global__ __launch_bounds__(512) void scores_kernel(
    const float* __restrict__ exT, const float* __restrict__ erT,
    const float* __restrict__ v_w, float* __restrict__ scT) {
  // layout: xs0[32*64] rs0[32*64] xs1[32*64] rs1[32*64] vsh[256]
  __shared__ float smem[4 * 2048 + 256];
  int b = blockIdx.z;
  int x0 = blockIdx.x * 64, r0 = blockIdx.y * 64;
  int tid = threadIdx.x;
  int g = tid >> 8;      // reduction group
  int t = tid & 255;
  float* xs = smem + g * 4096;   // [32][64]
  float* rs = xs + 2048;         // [32][64]
  float* vsh = smem + 8192;
  if (tid < 256) vsh[tid] = v_w[tid];
  int tx = t & 15, ty = t >> 4;  // tx -> x(4), ty -> r(4)
  int sr = t >> 4, sc = (t & 15) * 4;  // staging: 16 rows x 16 float4
  int wrot = (tid >> 6) & 7;     // 8 waves -> rotate hq by 0..7
  const float* pX = exT + (size_t)b * CH * CNX + x0 + sc;
  const float* pR = erT + (size_t)b * CH * CNR + r0 + sc;
  int hb = g * 32;
  float4 xa0 = *(const float4*)(pX + (size_t)(hb + sr) * CNX);
  float4 xa1 = *(const float4*)(pX + (size_t)(hb + sr + 16) * CNX);
  float4 ra0 = *(const float4*)(pR + (size_t)(hb + sr) * CNR);
  float4 ra1 = *(const float4*)(pR + (size_t)(hb + sr + 16) * CNR);
  float acc[4][4] = {};
  for (int hc = hb; hc < CH; hc += 64) {
    __syncthreads();
    *(float4*)&xs[sr * 64 + sc] = xa0;
    *(float4*)&xs[(sr + 16) * 64 + sc] = xa1;
    *(float4*)&rs[sr * 64 + sc] = ra0;
    *(float4*)&rs[(sr + 16) * 64 + sc] = ra1;
    __syncthreads();
    if (hc + 64 < CH) {
      xa0 = *(const float4*)(pX + (size_t)(hc + 64 + sr) * CNX);
      xa1 = *(const float4*)(pX + (size_t)(hc + 64 + sr + 16) * CNX);
      ra0 = *(const float4*)(pR + (size_t)(hc + 64 + sr) * CNR);
      ra1 = *(const float4*)(pR + (size_t)(hc + 64 + sr + 16) * CNR);
    }
#pragma unroll 2
    for (int hq = 0; hq < 8; hq++) {
      int h0 = ((hq + wrot) & 7) * 4;
      float4 vv = *(const float4*)&vsh[hc + h0];
      float4 xv0 = *(const float4*)&xs[(h0 + 0) * 64 + tx * 4];
      float4 xv1 = *(const float4*)&xs[(h0 + 1) * 64 + tx * 4];
      float4 xv2 = *(const float4*)&xs[(h0 + 2) * 64 + tx * 4];
      float4 xv3 = *(const float4*)&xs[(h0 + 3) * 64 + tx * 4];
      float4 rv0 = *(const float4*)&rs[(h0 + 0) * 64 + ty * 4];
      float4 rv1 = *(const float4*)&rs[(h0 + 1) * 64 + ty * 4];
      float4 rv2 = *(const float4*)&rs[(h0 + 2) * 64 + ty * 4];
      float4 rv3 = *(const float4*)&rs[(h0 + 3) * 64 + ty * 4];
      float xm0[4] = {xv0.x, xv0.y, xv0.z, xv0.w};
      float xm1[4] = {xv1.x, xv1.y, xv1.z, xv1.w};
      float xm2[4] = {xv2.x, xv2.y, xv2.z, xv2.w};
      float xm3[4] = {xv3.x, xv3.y, xv3.z, xv3.w};
      float rm0[4] = {rv0.x, rv0.y, rv0.z, rv0.w};
      float rm1[4] = {rv1.x, rv1.y, rv1.z, rv1.w};
      float rm2[4] = {rv2.x, rv2.y, rv2.z, rv2.w};
      float rm3[4] = {rv3.x, rv3.y, rv3.z, rv3.w};
#pragma unroll
      for (int i = 0; i < 4; i++)
#pragma unroll
        for (int j = 0; j < 4; j++) {
          float a = fmaf(rm0[i], xm0[j], 1.0f);
          float bb = fmaf(rm1[i], xm1[j], 1.0f);
          float c = fmaf(rm2[i], xm2[j], 1.0f);
          float d = fmaf(rm3[i], xm3[j], 1.0f);
          float q12 = a * bb, q34 = c * d;
          float p12 = fmaf(vv.y, a, vv.x * bb);
          float p34 = fmaf(vv.w, c, vv.z * d);
          float num = fmaf(p34, q12, p12 * q34);
          acc[i][j] = fmaf(num, fast_rcp(q12 * q34), acc[i][j]);
        }
    }
  }
  // merge the two h-partials (reuse smem[0..4096) after barrier)
  __syncthreads();
  float* mg = smem;
  if (g == 1) {
#pragma unroll
    for (int i = 0; i < 4; i++)
#pragma unroll
      for (int j = 0; j < 4; j++)
        mg[t + 256 * (i * 4 + j)] = acc[i][j];
  }
  __syncthreads();
  if (g == 0) {
    float* pO = scT + ((size_t)b * CNR + r0 + ty * 4) * CNX + x0 + tx * 4;
#pragma unroll
    for (int i = 0; i < 4; i++) {
      float4 o = {-2.0f * (acc[i][0] + mg[t + 256 * (i * 4 + 0)]),
                  -2.0f * (acc[i][1] + mg[t + 256 * (i * 4 + 1)]),
                  -2.0f * (acc[i][2] + mg[t + 256 * (i * 4 + 2)]),
                  -2.0f * (acc[i][3] + mg[t + 256 * (i * 4 + 3)])};
      *(float4*)(pO + (size_t)i * CNX) = o;
    }
  }
}

// Fused softmax + weighted sum via split-bf16 MFMA (r6 champion version).
// 64(r) x 64(d) tile, K-step 32(x), grid (8,4,8)=256 blocks, block 512.
__global__ __launch_bounds__(512) void wsum_mfma(
    const float* __restrict__ scT, const float* __restrict__ X,
    float* __restrict__ out) {
  // [buf][mat: P, Xt][row][64 ushort]; row = [hi 32k | lo 32k]
  __shared__ unsigned short lds[2][2][64][64];
  __shared__ float dn[64];
  const float L2E = 1.4426950408889634f;
  int b = blockIdx.z;
  int r0 = blockIdx.x * 64, d0 = blockIdx.y * 64;
  int tid = threadIdx.x;
  int lane = tid & 63, w = tid >> 6;
  int wm = w >> 2, wn = w & 3;  // r-half (32), d-quarter (16)
  int pr = tid >> 3, pxk = (tid & 7) * 4;
  int psl = pxk >> 3, pof = pxk & 7;
  int xd = tid & 63, xx = (tid >> 6) * 4;
  int xsl = xx >> 3, xof = xx & 7;
  const float* pS = scT + ((size_t)b * CNR + r0 + pr) * CNX + pxk;
  const float* pX = X + ((size_t)b * CNX + xx) * CD + d0 + xd;
  f32x4 acc0 = {}, acc1 = {};
  float dsum = 0.0f;
  float4 sv = *(const float4*)(pS);
  float4 xv = {pX[0], pX[CD], pX[2 * CD], pX[3 * CD]};
  {
    float4 ev = {fast_exp2(sv.x * L2E), fast_exp2(sv.y * L2E),
                 fast_exp2(sv.z * L2E), fast_exp2(sv.w * L2E)};
    dsum += (ev.x + ev.y) + (ev.z + ev.w);
    ushort4 H, L;
    split4(ev, &H, &L);
    unsigned short* rp = &lds[0][0][pr][0];
    *(ushort4*)(rp + ((psl ^ (pr & 7)) << 3) + pof) = H;
    *(ushort4*)(rp + (((psl + 4) ^ (pr & 7)) << 3) + pof) = L;
    split4(xv, &H, &L);
    unsigned short* rx = &lds[0][1][xd][0];
    *(ushort4*)(rx + ((xsl ^ (xd & 7)) << 3) + xof) = H;
    *(ushort4*)(rx + (((xsl + 4) ^ (xd & 7)) << 3) + xof) = L;
  }
  int q = lane >> 4;            // k-slot 0..3
  int mr0 = wm * 32 + (lane & 15);
  int mr1 = mr0 + 16;
  int nr = wn * 16 + (lane & 15);
  for (int s = 0; s < 16; s++) {
    __syncthreads();
    if (s < 15) {
      int kt = (s + 1) * 32;
      sv = *(const float4*)(pS + kt);
      xv.x = pX[(size_t)(kt + 0) * CD];
      xv.y = pX[(size_t)(kt + 1) * CD];
      xv.z = pX[(size_t)(kt + 2) * CD];
      xv.w = pX[(size_t)(kt + 3) * CD];
    }
    int cur = s & 1;
    const unsigned short* Pt = &lds[cur][0][0][0];
    const unsigned short* Xt = &lds[cur][1][0][0];
    short8 ah0 = *(const short8*)(Pt + mr0 * 64 + ((q ^ (mr0 & 7)) << 3));
    short8 al0 = *(const short8*)(Pt + mr0 * 64 + (((q + 4) ^ (mr0 & 7)) << 3));
    short8 ah1 = *(const short8*)(Pt + mr1 * 64 + ((q ^ (mr1 & 7)) << 3));
    short8 al1 = *(const short8*)(Pt + mr1 * 64 + (((q + 4) ^ (mr1 & 7)) << 3));
    short8 bh = *(const short8*)(Xt + nr * 64 + ((q ^ (nr & 7)) << 3));
    short8 bl = *(const short8*)(Xt + nr * 64 + (((q + 4) ^ (nr & 7)) << 3));
    acc0 = __builtin_amdgcn_mfma_f32_16x16x32_bf16(ah0, bh, acc0, 0, 0, 0);
    acc1 = __builtin_amdgcn_mfma_f32_16x16x32_bf16(ah1, bh, acc1, 0, 0, 0);
    acc0 = __builtin_amdgcn_mfma_f32_16x16x32_bf16(ah0, bl, acc0, 0, 0, 0);
    acc1 = __builtin_amdgcn_mfma_f32_16x16x32_bf16(ah1, bl, acc1, 0, 0, 0);
    acc0 = __builtin_amdgcn_mfma_f32_16x16x32_bf16(al0, bh, acc0, 0, 0, 0);
    acc1 = __builtin_amdgcn_mfma_f32_16x16x32_bf16(al1, bh, acc1, 0, 0, 0);
    if (s < 15) {
      int nxt = cur ^ 1;
      float4 ev = {fast_exp2(sv.x * L2E), fast_exp2(sv.y * L2E),
                   fast_exp2(sv.z * L2E), fast_exp2(sv.w * L2E)};
      dsum += (ev.x + ev.y) + (ev.z + ev.w);
      ushort4 H, L;
      split4(ev, &H, &L);
      unsigned short* rp = &lds[nxt][0][pr][0];
      *(ushort4*)(rp + ((psl ^ (pr & 7)) << 3) + pof) = H;
      *(ushort4*)(rp + (((psl + 4) ^ (pr & 7)) << 3) + pof) = L;
      split4(xv, &H, &L);
      unsigned short* rx = &lds[nxt][1][xd][0];
      *(ushort4*)(rx + ((xsl ^ (xd & 7)) << 3) + xof) = H;
      *(ushort4*)(rx + (((xsl + 4) ^ (xd & 7)) << 3) + xof) = L;
    }
  }
  // denominator: 8 threads (tid&7) share row pr
  dsum += __shfl_xor(dsum, 1, 64);
  dsum += __shfl_xor(dsum, 2, 64);
  dsum += __shfl_xor(dsum, 4, 64);
  if ((tid & 7) == 0) dn[pr] = dsum;
  __syncthreads();
  int col = d0 + wn * 16 + (lane & 15);
  float* pO = out + ((size_t)b * CNR + r0) * CD + col;
#pragma unroll
  for (int j = 0; j < 4; j++) {
    int row = wm * 32 + q * 4 + j;
    pO[(size_t)row * CD] = acc0[j] * fast_rcp(dn[row]);
  }
#pragma unroll
  for (int j = 0; j < 4; j++) {
    int row = wm * 32 + 16 + q * 4 + j;
    pO[(size_t)row * CD] = acc1[j] * fast_rcp(dn[row]);
  }
}

extern "C" void kernel_launch(void* const* d_in, const int* in_sizes, int n_in,
                              void* d_out, int out_size, void* d_ws, size_t ws_size,
                              hipStream_t stream) {
  const float* X     = (const float*)d_in[0];
  const float* ref   = (const float*)d_in[1];
  const float* W_X   = (const float*)d_in[2];
  const float* b_X   = (const float*)d_in[3];
  const float* W_ref = (const float*)d_in[4];
  const float* b_ref = (const float*)d_in[5];
  const float* v_w   = (const float*)d_in[6];
  float* out = (float*)d_out;
  float* ws  = (float*)d_ws;

  float* exT = ws;                       // [B][H][NX] = 1,048,576 floats
  float* erT = ws + 1048576;             // [B][H][NR] = 1,048,576 floats
  float* scT = ws + 2097152;             // [B][NR][NX] = 2,097,152 floats

  proj_mfma<<<dim3(64, 4, 2), 256, 0, stream>>>(X, ref, W_X, W_ref, b_X, b_ref, exT, erT);
  scores_kernel<<<dim3(8, 8, 8), 512, 0, stream>>>(exT, erT, v_w, scT);
  wsum_mfma<<<dim3(8, 4, 8), 512, 0, stream>>>(scT, X, out);
}

// Round 16
// 134.554 us; speedup vs baseline: 1.1679x; 1.0084x over previous
//
#include <hip/hip_runtime.h>
#include <math.h>

#define CB 8
#define CNX 512
#define CNR 512
#define CD 256
#define CH 256

typedef __attribute__((ext_vector_type(8))) short short8;
typedef __attribute__((ext_vector_type(4))) float f32x4;
typedef __attribute__((ext_vector_type(4))) unsigned int uint32x4;

__device__ __forceinline__ float fast_rcp(float x) {
#if __has_builtin(__builtin_amdgcn_rcpf)
  return __builtin_amdgcn_rcpf(x);
#else
  return 1.0f / x;
#endif
}
__device__ __forceinline__ float fast_exp2(float x) {
#if __has_builtin(__builtin_amdgcn_exp2f)
  return __builtin_amdgcn_exp2f(x);
#else
  return exp2f(x);
#endif
}

// Split a float into bf16 hi (truncation) + bf16 lo (residual, truncated),
// packing 8 consecutive k-values into uint4 hi and uint4 lo, store to LDS.
__device__ __forceinline__ void cvt_store(unsigned short* dstH,
                                          unsigned short* dstL,
                                          float4 v0, float4 v1) {
  unsigned u0x = __float_as_uint(v0.x), u0y = __float_as_uint(v0.y);
  unsigned u0z = __float_as_uint(v0.z), u0w = __float_as_uint(v0.w);
  unsigned u1x = __float_as_uint(v1.x), u1y = __float_as_uint(v1.y);
  unsigned u1z = __float_as_uint(v1.z), u1w = __float_as_uint(v1.w);
  uint4 H;
  H.x = (u0x >> 16) | (u0y & 0xFFFF0000u);
  H.y = (u0z >> 16) | (u0w & 0xFFFF0000u);
  H.z = (u1x >> 16) | (u1y & 0xFFFF0000u);
  H.w = (u1z >> 16) | (u1w & 0xFFFF0000u);
  float r0x = v0.x - __uint_as_float(u0x & 0xFFFF0000u);
  float r0y = v0.y - __uint_as_float(u0y & 0xFFFF0000u);
  float r0z = v0.z - __uint_as_float(u0z & 0xFFFF0000u);
  float r0w = v0.w - __uint_as_float(u0w & 0xFFFF0000u);
  float r1x = v1.x - __uint_as_float(u1x & 0xFFFF0000u);
  float r1y = v1.y - __uint_as_float(u1y & 0xFFFF0000u);
  float r1z = v1.z - __uint_as_float(u1z & 0xFFFF0000u);
  float r1w = v1.w - __uint_as_float(u1w & 0xFFFF0000u);
  uint4 L;
  L.x = (__float_as_uint(r0x) >> 16) | (__float_as_uint(r0y) & 0xFFFF0000u);
  L.y = (__float_as_uint(r0z) >> 16) | (__float_as_uint(r0w) & 0xFFFF0000u);
  L.z = (__float_as_uint(r1x) >> 16) | (__float_as_uint(r1y) & 0xFFFF0000u);
  L.w = (__float_as_uint(r1z) >> 16) | (__float_as_uint(r1w) & 0xFFFF0000u);
  *(uint4*)dstH = H;
  *(uint4*)dstL = L;
}

// Split 8 fp32 (two float4) into bf16 hi / lo short8 (register-only).
__device__ __forceinline__ void split8(float4 u, float4 v, short8* H, short8* L) {
  unsigned ux = __float_as_uint(u.x), uy = __float_as_uint(u.y);
  unsigned uz = __float_as_uint(u.z), uw = __float_as_uint(u.w);
  unsigned vx = __float_as_uint(v.x), vy = __float_as_uint(v.y);
  unsigned vz = __float_as_uint(v.z), vw = __float_as_uint(v.w);
  uint32x4 Hp = {(ux >> 16) | (uy & 0xFFFF0000u),
                 (uz >> 16) | (uw & 0xFFFF0000u),
                 (vx >> 16) | (vy & 0xFFFF0000u),
                 (vz >> 16) | (vw & 0xFFFF0000u)};
  float rux = u.x - __uint_as_float(ux & 0xFFFF0000u);
  float ruy = u.y - __uint_as_float(uy & 0xFFFF0000u);
  float ruz = u.z - __uint_as_float(uz & 0xFFFF0000u);
  float ruw = u.w - __uint_as_float(uw & 0xFFFF0000u);
  float rvx = v.x - __uint_as_float(vx & 0xFFFF0000u);
  float rvy = v.y - __uint_as_float(vy & 0xFFFF0000u);
  float rvz = v.z - __uint_as_float(vz & 0xFFFF0000u);
  float rvw = v.w - __uint_as_float(vw & 0xFFFF0000u);
  uint32x4 Lp = {(__float_as_uint(rux) >> 16) | (__float_as_uint(ruy) & 0xFFFF0000u),
                 (__float_as_uint(ruz) >> 16) | (__float_as_uint(ruw) & 0xFFFF0000u),
                 (__float_as_uint(rvx) >> 16) | (__float_as_uint(rvy) & 0xFFFF0000u),
                 (__float_as_uint(rvz) >> 16) | (__float_as_uint(rvw) & 0xFFFF0000u)};
  *H = __builtin_bit_cast(short8, Hp);
  *L = __builtin_bit_cast(short8, Lp);
}

// Fused projections via split-bf16 MFMA (3 mfma: hi*hi + hi*lo + lo*hi).
// r6 champion version: 64x64 tile, K-step 32, LDS double-buffered.
__global__ __launch_bounds__(256) void proj_mfma(
    const float* __restrict__ A0, const float* __restrict__ A1,
    const float* __restrict__ W0, const float* __restrict__ W1,
    const float* __restrict__ bias0, const float* __restrict__ bias1,
    float* __restrict__ E0, float* __restrict__ E1) {
  // [buf][mat: Ah,Al,Wh,Wl][row][k] ; row stride 40 ushort = 80 B
  __shared__ unsigned short lds[2][4][64][40];
  const int K = CD;
  int z = blockIdx.z;
  const float* A = z ? A1 : A0;
  const float* W = z ? W1 : W0;
  const float* bias = z ? bias1 : bias0;
  float* ET = z ? E1 : E0;
  int m0 = blockIdx.x * 64, n0 = blockIdx.y * 64;
  int tid = threadIdx.x;
  int lane = tid & 63, w = tid >> 6;
  int wm = w >> 1, wn = w & 1;  // wave quadrant: m-half, n-half
  int r = tid >> 2, kq = (tid & 3) * 8;
  const float* pA = A + (size_t)(m0 + r) * K + kq;
  const float* pW = W + (size_t)(n0 + r) * K + kq;
  f32x4 acc[2][2] = {};
  float4 a0 = *(const float4*)(pA);
  float4 a1 = *(const float4*)(pA + 4);
  float4 w0 = *(const float4*)(pW);
  float4 w1 = *(const float4*)(pW + 4);
  cvt_store(&lds[0][0][r][kq], &lds[0][1][r][kq], a0, a1);
  cvt_store(&lds[0][2][r][kq], &lds[0][3][r][kq], w0, w1);
  for (int s = 0; s < 8; s++) {
    __syncthreads();
    if (s < 7) {
      int kt = (s + 1) * 32;
      a0 = *(const float4*)(pA + kt);
      a1 = *(const float4*)(pA + kt + 4);
      w0 = *(const float4*)(pW + kt);
      w1 = *(const float4*)(pW + kt + 4);
    }
    int cur = s & 1;
    int arow = wm * 32 + (lane & 15);
    int brow = wn * 32 + (lane & 15);
    int koff = (lane >> 4) * 8;
    short8 ah0 = *(const short8*)&lds[cur][0][arow][koff];
    short8 ah1 = *(const short8*)&lds[cur][0][arow + 16][koff];
    short8 al0 = *(const short8*)&lds[cur][1][arow][koff];
    short8 al1 = *(const short8*)&lds[cur][1][arow + 16][koff];
    short8 bh0 = *(const short8*)&lds[cur][2][brow][koff];
    short8 bh1 = *(const short8*)&lds[cur][2][brow + 16][koff];
    short8 bl0 = *(const short8*)&lds[cur][3][brow][koff];
    short8 bl1 = *(const short8*)&lds[cur][3][brow + 16][koff];
    acc[0][0] = __builtin_amdgcn_mfma_f32_16x16x32_bf16(ah0, bh0, acc[0][0], 0, 0, 0);
    acc[0][1] = __builtin_amdgcn_mfma_f32_16x16x32_bf16(ah0, bh1, acc[0][1], 0, 0, 0);
    acc[1][0] = __builtin_amdgcn_mfma_f32_16x16x32_bf16(ah1, bh0, acc[1][0], 0, 0, 0);
    acc[1][1] = __builtin_amdgcn_mfma_f32_16x16x32_bf16(ah1, bh1, acc[1][1], 0, 0, 0);
    acc[0][0] = __builtin_amdgcn_mfma_f32_16x16x32_bf16(ah0, bl0, acc[0][0], 0, 0, 0);
    acc[0][1] = __builtin_amdgcn_mfma_f32_16x16x32_bf16(ah0, bl1, acc[0][1], 0, 0, 0);
    acc[1][0] = __builtin_amdgcn_mfma_f32_16x16x32_bf16(ah1, bl0, acc[1][0], 0, 0, 0);
    acc[1][1] = __builtin_amdgcn_mfma_f32_16x16x32_bf16(ah1, bl1, acc[1][1], 0, 0, 0);
    acc[0][0] = __builtin_amdgcn_mfma_f32_16x16x32_bf16(al0, bh0, acc[0][0], 0, 0, 0);
    acc[0][1] = __builtin_amdgcn_mfma_f32_16x16x32_bf16(al0, bh1, acc[0][1], 0, 0, 0);
    acc[1][0] = __builtin_amdgcn_mfma_f32_16x16x32_bf16(al1, bh0, acc[1][0], 0, 0, 0);
    acc[1][1] = __builtin_amdgcn_mfma_f32_16x16x32_bf16(al1, bh1, acc[1][1], 0, 0, 0);
    if (s < 7) {
      int nxt = cur ^ 1;
      cvt_store(&lds[nxt][0][r][kq], &lds[nxt][1][r][kq], a0, a1);
      cvt_store(&lds[nxt][2][r][kq], &lds[nxt][3][r][kq], w0, w1);
    }
  }
  const float K2L = 2.8853900817779268f;  // 2*log2(e)
  int b = m0 >> 9;
  int xq = (m0 & 511) + wm * 32 + (lane >> 4) * 4;
#pragma unroll
  for (int mi = 0; mi < 2; mi++) {
#pragma unroll
    for (int ni = 0; ni < 2; ni++) {
      int h = n0 + wn * 32 + ni * 16 + (lane & 15);
      float bb = bias[h];
      f32x4 a = acc[mi][ni];
      float4 o = {fast_exp2(K2L * (a[0] + bb)), fast_exp2(K2L * (a[1] + bb)),
                  fast_exp2(K2L * (a[2] + bb)), fast_exp2(K2L * (a[3] + bb))};
      *(float4*)(ET + ((size_t)b * CH + h) * CNX + xq + mi * 16) = o;
    }
  }
}

// scT[b][r][x] = -2 * sum_h v_w[h] / (exT[b][h][x]*erT[b][h][r] + 1)
// v4 (proven 51.4-52.2us): 64(x) x 64(r) tile, grid (8,8,8)=512 blocks,
// block 512 (two 256-thread groups h-splitting), 4x4 microtile.
__global__ __launch_bounds__(512) void scores_kernel(
    const float* __restrict__ exT, const float* __restrict__ erT,
    const float* __restrict__ v_w, float* __restrict__ scT) {
  // layout: xs0[32*64] rs0[32*64] xs1[32*64] rs1[32*64] vsh[256]
  __shared__ float smem[4 * 2048 + 256];
  int b = blockIdx.z;
  int x0 = blockIdx.x * 64, r0 = blockIdx.y * 64;
  int tid = threadIdx.x;
  int g = tid >> 8;      // reduction group
  int t = tid & 255;
  float* xs = smem + g * 4096;   // [32][64]
  float* rs = xs + 2048;         // [32][64]
  float* vsh = smem + 8192;
  if (tid < 256) vsh[tid] = v_w[tid];
  int tx = t & 15, ty = t >> 4;  // tx -> x(4), ty -> r(4)
  int sr = t >> 4, sc = (t & 15) * 4;  // staging: 16 rows x 16 float4
  int wrot = (tid >> 6) & 7;     // 8 waves -> rotate hq by 0..7
  const float* pX = exT + (size_t)b * CH * CNX + x0 + sc;
  const float* pR = erT + (size_t)b * CH * CNR + r0 + sc;
  int hb = g * 32;
  float4 xa0 = *(const float4*)(pX + (size_t)(hb + sr) * CNX);
  float4 xa1 = *(const float4*)(pX + (size_t)(hb + sr + 16) * CNX);
  float4 ra0 = *(const float4*)(pR + (size_t)(hb + sr) * CNR);
  float4 ra1 = *(const float4*)(pR + (size_t)(hb + sr + 16) * CNR);
  float acc[4][4] = {};
  for (int hc = hb; hc < CH; hc += 64) {
    __syncthreads();
    *(float4*)&xs[sr * 64 + sc] = xa0;
    *(float4*)&xs[(sr + 16) * 64 + sc] = xa1;
    *(float4*)&rs[sr * 64 + sc] = ra0;
    *(float4*)&rs[(sr + 16) * 64 + sc] = ra1;
    __syncthreads();
    if (hc + 64 < CH) {
      xa0 = *(const float4*)(pX + (size_t)(hc + 64 + sr) * CNX);
      xa1 = *(const float4*)(pX + (size_t)(hc + 64 + sr + 16) * CNX);
      ra0 = *(const float4*)(pR + (size_t)(hc + 64 + sr) * CNR);
      ra1 = *(const float4*)(pR + (size_t)(hc + 64 + sr + 16) * CNR);
    }
#pragma unroll 2
    for (int hq = 0; hq < 8; hq++) {
      int h0 = ((hq + wrot) & 7) * 4;
      float4 vv = *(const float4*)&vsh[hc + h0];
      float4 xv0 = *(const float4*)&xs[(h0 + 0) * 64 + tx * 4];
      float4 xv1 = *(const float4*)&xs[(h0 + 1) * 64 + tx * 4];
      float4 xv2 = *(const float4*)&xs[(h0 + 2) * 64 + tx * 4];
      float4 xv3 = *(const float4*)&xs[(h0 + 3) * 64 + tx * 4];
      float4 rv0 = *(const float4*)&rs[(h0 + 0) * 64 + ty * 4];
      float4 rv1 = *(const float4*)&rs[(h0 + 1) * 64 + ty * 4];
      float4 rv2 = *(const float4*)&rs[(h0 + 2) * 64 + ty * 4];
      float4 rv3 = *(const float4*)&rs[(h0 + 3) * 64 + ty * 4];
      float xm0[4] = {xv0.x, xv0.y, xv0.z, xv0.w};
      float xm1[4] = {xv1.x, xv1.y, xv1.z, xv1.w};
      float xm2[4] = {xv2.x, xv2.y, xv2.z, xv2.w};
      float xm3[4] = {xv3.x, xv3.y, xv3.z, xv3.w};
      float rm0[4] = {rv0.x, rv0.y, rv0.z, rv0.w};
      float rm1[4] = {rv1.x, rv1.y, rv1.z, rv1.w};
      float rm2[4] = {rv2.x, rv2.y, rv2.z, rv2.w};
      float rm3[4] = {rv3.x, rv3.y, rv3.z, rv3.w};
#pragma unroll
      for (int i = 0; i < 4; i++)
#pragma unroll
        for (int j = 0; j < 4; j++) {
          float a = fmaf(rm0[i], xm0[j], 1.0f);
          float bb = fmaf(rm1[i], xm1[j], 1.0f);
          float c = fmaf(rm2[i], xm2[j], 1.0f);
          float d = fmaf(rm3[i], xm3[j], 1.0f);
          float q12 = a * bb, q34 = c * d;
          float p12 = fmaf(vv.y, a, vv.x * bb);
          float p34 = fmaf(vv.w, c, vv.z * d);
          float num = fmaf(p34, q12, p12 * q34);
          acc[i][j] = fmaf(num, fast_rcp(q12 * q34), acc[i][j]);
        }
    }
  }
  // merge the two h-partials (reuse smem[0..4096) after barrier)
  __syncthreads();
  float* mg = smem;
  if (g == 1) {
#pragma unroll
    for (int i = 0; i < 4; i++)
#pragma unroll
      for (int j = 0; j < 4; j++)
        mg[t + 256 * (i * 4 + j)] = acc[i][j];
  }
  __syncthreads();
  if (g == 0) {
    float* pO = scT + ((size_t)b * CNR + r0 + ty * 4) * CNX + x0 + tx * 4;
#pragma unroll
    for (int i = 0; i < 4; i++) {
      float4 o = {-2.0f * (acc[i][0] + mg[t + 256 * (i * 4 + 0)]),
                  -2.0f * (acc[i][1] + mg[t + 256 * (i * 4 + 1)]),
                  -2.0f * (acc[i][2] + mg[t + 256 * (i * 4 + 2)]),
                  -2.0f * (acc[i][3] + mg[t + 256 * (i * 4 + 3)])};
      *(float4*)(pO + (size_t)i * CNX) = o;
    }
  }
}

// Fused softmax + weighted sum via split-bf16 MFMA. v3: K-step 64 -> 8
// barrier-phases instead of 16 (grid = 256 = 1 block/CU, so the bigger
// 64KB LDS is free). Row = [hi 64k | lo 64k] = 16 swizzled 16B slots.
// 64(r) x 64(d) tile, grid (8,4,8), block 512 = 8 waves (2r x 4d).
__global__ __launch_bounds__(512) void wsum_mfma(
    const float* __restrict__ scT, const float* __restrict__ X,
    float* __restrict__ out) {
  // [buf][mat: P, Xt][row][128 ushort]
  __shared__ unsigned short lds[2][2][64][128];
  __shared__ float dn[64];
  const float L2E = 1.4426950408889634f;
  int b = blockIdx.z;
  int r0 = blockIdx.x * 64, d0 = blockIdx.y * 64;
  int tid = threadIdx.x;
  int lane = tid & 63, w = tid >> 6;
  int wm = w >> 2, wn = w & 3;  // r-half (32), d-quarter (16)
  // P staging: row pr (64), 8 k per thread = one hi slot + one lo slot
  int pr = tid >> 3, psl = tid & 7;      // slot 0..7, k = psl*8
  // X staging: d-row xd (64), 8 x per thread (in-register transpose)
  int xd = lane, xsl = w;                // slot 0..7, x = xsl*8
  const float* pS = scT + ((size_t)b * CNR + r0 + pr) * CNX + psl * 8;
  const float* pX = X + ((size_t)b * CNX + xsl * 8) * CD + d0 + xd;
  f32x4 acc0 = {}, acc1 = {};
  float dsum = 0.0f;
  int pslot = (psl ^ (pr & 7)) * 8;      // ushort offset of hi slot
  int xslot = (xsl ^ (xd & 7)) * 8;
  // initial stage (kt = 0)
  {
    float4 s0 = *(const float4*)(pS);
    float4 s1 = *(const float4*)(pS + 4);
    float4 e0 = {fast_exp2(s0.x * L2E), fast_exp2(s0.y * L2E),
                 fast_exp2(s0.z * L2E), fast_exp2(s0.w * L2E)};
    float4 e1 = {fast_exp2(s1.x * L2E), fast_exp2(s1.y * L2E),
                 fast_exp2(s1.z * L2E), fast_exp2(s1.w * L2E)};
    dsum += ((e0.x + e0.y) + (e0.z + e0.w)) + ((e1.x + e1.y) + (e1.z + e1.w));
    short8 H, L;
    split8(e0, e1, &H, &L);
    *(short8*)(&lds[0][0][pr][pslot]) = H;
    *(short8*)(&lds[0][0][pr][64 + pslot]) = L;
    float4 xa = {pX[0], pX[CD], pX[2 * CD], pX[3 * CD]};
    float4 xb = {pX[4 * CD], pX[5 * CD], pX[6 * CD], pX[7 * CD]};
    split8(xa, xb, &H, &L);
    *(short8*)(&lds[0][1][xd][xslot]) = H;
    *(short8*)(&lds[0][1][xd][64 + xslot]) = L;
  }
  int q = lane >> 4;            // k-subslot 0..3
  int mr0 = wm * 32 + (lane & 15);
  int mr1 = mr0 + 16;
  int nr = wn * 16 + (lane & 15);
  int sa0 = (q ^ (mr0 & 7)) * 8, sa0b = ((q + 4) ^ (mr0 & 7)) * 8;
  int sa1 = (q ^ (mr1 & 7)) * 8, sa1b = ((q + 4) ^ (mr1 & 7)) * 8;
  int sb = (q ^ (nr & 7)) * 8, sbb = ((q + 4) ^ (nr & 7)) * 8;
  for (int s = 0; s < 8; s++) {
    __syncthreads();
    float4 s0, s1, xa, xb;
    if (s < 7) {
      int kt = (s + 1) * 64;
      s0 = *(const float4*)(pS + kt);
      s1 = *(const float4*)(pS + kt + 4);
      xa.x = pX[(size_t)(kt + 0) * CD];
      xa.y = pX[(size_t)(kt + 1) * CD];
      xa.z = pX[(size_t)(kt + 2) * CD];
      xa.w = pX[(size_t)(kt + 3) * CD];
      xb.x = pX[(size_t)(kt + 4) * CD];
      xb.y = pX[(size_t)(kt + 5) * CD];
      xb.z = pX[(size_t)(kt + 6) * CD];
      xb.w = pX[(size_t)(kt + 7) * CD];
    }
    int cur = s & 1;
    const unsigned short* Pt = &lds[cur][0][0][0];
    const unsigned short* Xt = &lds[cur][1][0][0];
    // kk = 0 (k 0..31 of this 64-step)
    {
      short8 ah0 = *(const short8*)(Pt + mr0 * 128 + sa0);
      short8 al0 = *(const short8*)(Pt + mr0 * 128 + 64 + sa0);
      short8 ah1 = *(const short8*)(Pt + mr1 * 128 + sa1);
      short8 al1 = *(const short8*)(Pt + mr1 * 128 + 64 + sa1);
      short8 bh = *(const short8*)(Xt + nr * 128 + sb);
      short8 bl = *(const short8*)(Xt + nr * 128 + 64 + sb);
      acc0 = __builtin_amdgcn_mfma_f32_16x16x32_bf16(ah0, bh, acc0, 0, 0, 0);
      acc1 = __builtin_amdgcn_mfma_f32_16x16x32_bf16(ah1, bh, acc1, 0, 0, 0);
      acc0 = __builtin_amdgcn_mfma_f32_16x16x32_bf16(ah0, bl, acc0, 0, 0, 0);
      acc1 = __builtin_amdgcn_mfma_f32_16x16x32_bf16(ah1, bl, acc1, 0, 0, 0);
      acc0 = __builtin_amdgcn_mfma_f32_16x16x32_bf16(al0, bh, acc0, 0, 0, 0);
      acc1 = __builtin_amdgcn_mfma_f32_16x16x32_bf16(al1, bh, acc1, 0, 0, 0);
    }
    // kk = 1 (k 32..63): slots offset by 4 within the hi/lo halves
    {
      short8 ah0 = *(const short8*)(Pt + mr0 * 128 + sa0b);
      short8 al0 = *(const short8*)(Pt + mr0 * 128 + 64 + sa0b);
      short8 ah1 = *(const short8*)(Pt + mr1 * 128 + sa1b);
      short8 al1 = *(const short8*)(Pt + mr1 * 128 + 64 + sa1b);
      short8 bh = *(const short8*)(Xt + nr * 128 + sbb);
      short8 bl = *(const short8*)(Xt + nr * 128 + 64 + sbb);
      acc0 = __builtin_amdgcn_mfma_f32_16x16x32_bf16(ah0, bh, acc0, 0, 0, 0);
      acc1 = __builtin_amdgcn_mfma_f32_16x16x32_bf16(ah1, bh, acc1, 0, 0, 0);
      acc0 = __builtin_amdgcn_mfma_f32_16x16x32_bf16(ah0, bl, acc0, 0, 0, 0);
      acc1 = __builtin_amdgcn_mfma_f32_16x16x32_bf16(ah1, bl, acc1, 0, 0, 0);
      acc0 = __builtin_amdgcn_mfma_f32_16x16x32_bf16(al0, bh, acc0, 0, 0, 0);
      acc1 = __builtin_amdgcn_mfma_f32_16x16x32_bf16(al1, bh, acc1, 0, 0, 0);
    }
    if (s < 7) {
      int nxt = cur ^ 1;
      float4 e0 = {fast_exp2(s0.x * L2E), fast_exp2(s0.y * L2E),
                   fast_exp2(s0.z * L2E), fast_exp2(s0.w * L2E)};
      float4 e1 = {fast_exp2(s1.x * L2E), fast_exp2(s1.y * L2E),
                   fast_exp2(s1.z * L2E), fast_exp2(s1.w * L2E)};
      dsum += ((e0.x + e0.y) + (e0.z + e0.w)) + ((e1.x + e1.y) + (e1.z + e1.w));
      short8 H, L;
      split8(e0, e1, &H, &L);
      *(short8*)(&lds[nxt][0][pr][pslot]) = H;
      *(short8*)(&lds[nxt][0][pr][64 + pslot]) = L;
      split8(xa, xb, &H, &L);
      *(short8*)(&lds[nxt][1][xd][xslot]) = H;
      *(short8*)(&lds[nxt][1][xd][64 + xslot]) = L;
    }
  }
  // denominator: 8 threads (tid&7) share row pr
  dsum += __shfl_xor(dsum, 1, 64);
  dsum += __shfl_xor(dsum, 2, 64);
  dsum += __shfl_xor(dsum, 4, 64);
  if ((tid & 7) == 0) dn[pr] = dsum;
  __syncthreads();
  int col = d0 + wn * 16 + (lane & 15);
  float* pO = out + ((size_t)b * CNR + r0) * CD + col;
#pragma unroll
  for (int j = 0; j < 4; j++) {
    int row = wm * 32 + q * 4 + j;
    pO[(size_t)row * CD] = acc0[j] * fast_rcp(dn[row]);
  }
#pragma unroll
  for (int j = 0; j < 4; j++) {
    int row = wm * 32 + 16 + q * 4 + j;
    pO[(size_t)row * CD] = acc1[j] * fast_rcp(dn[row]);
  }
}

extern "C" void kernel_launch(void* const* d_in, const int* in_sizes, int n_in,
                              void* d_out, int out_size, void* d_ws, size_t ws_size,
                              hipStream_t stream) {
  const float* X     = (const float*)d_in[0];
  const float* ref   = (const float*)d_in[1];
  const float* W_X   = (const float*)d_in[2];
  const float* b_X   = (const float*)d_in[3];
  const float* W_ref = (const float*)d_in[4];
  const float* b_ref = (const float*)d_in[5];
  const float* v_w   = (const float*)d_in[6];
  float* out = (float*)d_out;
  float* ws  = (float*)d_ws;

  float* exT = ws;                       // [B][H][NX] = 1,048,576 floats
  float* erT = ws + 1048576;             // [B][H][NR] = 1,048,576 floats
  float* scT = ws + 2097152;             // [B][NR][NX] = 2,097,152 floats

  proj_mfma<<<dim3(64, 4, 2), 256, 0, stream>>>(X, ref, W_X, W_ref, b_X, b_ref, exT, erT);
  scores_kernel<<<dim3(8, 8, 8), 512, 0, stream>>>(exT, erT, v_w, scT);
  wsum_mfma<<<dim3(8, 4, 8), 512, 0, stream>>>(scT, X, out);
}